// Round 1
// baseline (18905.258 us; speedup 1.0000x reference)
//
#include <hip/hip_runtime.h>

#define N_NODES 50000
#define N_EDGES 800000
#define F_INPUT 3
#define H 256
#define G_BATCH 64
#define OUT_DIM 24

// ---------------- layer 1 (F_IN=3 -> H) ----------------

__global__ void scatter3(const float* __restrict__ x, const int* __restrict__ src,
                         const int* __restrict__ dst, float* __restrict__ agg) {
    int e = blockIdx.x * blockDim.x + threadIdx.x;
    if (e >= N_EDGES) return;
    int s = src[e], d = dst[e];
    atomicAdd(&agg[d * 3 + 0], x[s * 3 + 0]);
    atomicAdd(&agg[d * 3 + 1], x[s * 3 + 1]);
    atomicAdd(&agg[d * 3 + 2], x[s * 3 + 2]);
}

__global__ void layer1_kernel(const float* __restrict__ x, const float* __restrict__ agg,
                              const float* __restrict__ wr, const float* __restrict__ wro,
                              const float* __restrict__ bias, float* __restrict__ out) {
    int n = blockIdx.x;
    int f = threadIdx.x;
    float a0 = agg[n * 3 + 0], a1 = agg[n * 3 + 1], a2 = agg[n * 3 + 2];
    float x0 = x[n * 3 + 0], x1 = x[n * 3 + 1], x2 = x[n * 3 + 2];
    float v = bias[f];
    v += a0 * wr[0 * H + f] + a1 * wr[1 * H + f] + a2 * wr[2 * H + f];
    v += x0 * wro[0 * H + f] + x1 * wro[1 * H + f] + x2 * wro[2 * H + f];
    out[(size_t)n * H + f] = fmaxf(v, 0.f);
}

// ---------------- scatter-add for H=256 (one wave per edge) ----------------

__global__ void scatterH(const float* __restrict__ h, const int* __restrict__ src,
                         const int* __restrict__ dst, float* __restrict__ agg) {
    int gtid = blockIdx.x * blockDim.x + threadIdx.x;
    int e = gtid >> 6;
    int lane = threadIdx.x & 63;
    if (e >= N_EDGES) return;
    int s = src[e], d = dst[e];
    const float4 v = *(const float4*)(h + (size_t)s * H + lane * 4);
    float* o = agg + (size_t)d * H + lane * 4;
    atomicAdd(o + 0, v.x);
    atomicAdd(o + 1, v.y);
    atomicAdd(o + 2, v.z);
    atomicAdd(o + 3, v.w);
}

// ---------------- fused dual GEMM: C = relu(Aagg@Wr + Ah@Wo + bias) ----------------

#define BM 64
#define BN 64
#define BK 16

__global__ __launch_bounds__(256) void gemm_fused(
    const float* __restrict__ Aagg, const float* __restrict__ Ah,
    const float* __restrict__ Wr, const float* __restrict__ Wo,
    const float* __restrict__ bias, float* __restrict__ C, int M) {
    // A tiles stored [m][k] with pad to kill bank conflicts; W tiles [k][n].
    __shared__ float sAa[BM][BK + 1];
    __shared__ float sAh[BM][BK + 1];
    __shared__ float sWr[BK][BN];
    __shared__ float sWo[BK][BN];

    int tid = threadIdx.x;
    int tx = tid & 15;       // col group
    int ty = tid >> 4;       // row group
    int m0 = blockIdx.x * BM;
    int n0 = blockIdx.y * BN;

    float acc[4][4] = {};

    for (int k0 = 0; k0 < H; k0 += BK) {
        // A tiles: 64 rows x 16 k; thread t -> flat i, k fastest (global-coalesced)
        for (int i = tid; i < BM * BK; i += 256) {
            int m = i >> 4;
            int k = i & 15;
            int row = m0 + m;
            float va = 0.f, vh = 0.f;
            if (row < M) {
                va = Aagg[(size_t)row * H + k0 + k];
                vh = Ah[(size_t)row * H + k0 + k];
            }
            sAa[m][k] = va;
            sAh[m][k] = vh;
        }
        // W tiles: 16 k x 64 n; thread t -> n fastest (global-coalesced)
        for (int i = tid; i < BK * BN; i += 256) {
            int k = i >> 6;
            int n = i & 63;
            sWr[k][n] = Wr[(size_t)(k0 + k) * H + n0 + n];
            sWo[k][n] = Wo[(size_t)(k0 + k) * H + n0 + n];
        }
        __syncthreads();

#pragma unroll
        for (int k = 0; k < BK; ++k) {
            float a[4], hh[4], wr[4], wo[4];
#pragma unroll
            for (int i = 0; i < 4; i++) {
                a[i] = sAa[ty * 4 + i][k];
                hh[i] = sAh[ty * 4 + i][k];
            }
#pragma unroll
            for (int j = 0; j < 4; j++) {
                wr[j] = sWr[k][tx * 4 + j];
                wo[j] = sWo[k][tx * 4 + j];
            }
#pragma unroll
            for (int i = 0; i < 4; i++)
#pragma unroll
                for (int j = 0; j < 4; j++)
                    acc[i][j] += a[i] * wr[j] + hh[i] * wo[j];
        }
        __syncthreads();
    }

#pragma unroll
    for (int i = 0; i < 4; i++) {
        int row = m0 + ty * 4 + i;
        if (row >= M) continue;
#pragma unroll
        for (int j = 0; j < 4; j++) {
            int col = n0 + tx * 4 + j;
            float v = acc[i][j] + bias[col];
            C[(size_t)row * H + col] = fmaxf(v, 0.f);
        }
    }
}

// ---------------- pooling ----------------

__device__ __forceinline__ int lowerBound(const int* __restrict__ batch, int val) {
    int lo = 0, hi = N_NODES;
    while (lo < hi) {
        int mid = (lo + hi) >> 1;
        if (batch[mid] < val) lo = mid + 1; else hi = mid;
    }
    return lo;
}

__global__ void pool_partial(const float* __restrict__ h, const int* __restrict__ batch,
                             float* __restrict__ pooled) {
    int g = blockIdx.x;
    int seg = blockIdx.y;           // 0..7 segments of this graph's node range
    int f = threadIdx.x;            // 0..255
    int start = lowerBound(batch, g);
    int end = lowerBound(batch, g + 1);
    int len = end - start;
    int s0 = start + (int)((long long)len * seg / 8);
    int s1 = start + (int)((long long)len * (seg + 1) / 8);
    float sum = 0.f;
    for (int n = s0; n < s1; ++n)
        sum += h[(size_t)n * H + f];
    if (s1 > s0)
        atomicAdd(&pooled[g * H + f], sum);
}

__global__ void head_kernel(const float* __restrict__ pooled, const int* __restrict__ batch,
                            const float* __restrict__ w_out, const float* __restrict__ b_out,
                            float* __restrict__ out) {
    int g = blockIdx.x;
    int o = threadIdx.x;  // 0..23
    int start = lowerBound(batch, g);
    int end = lowerBound(batch, g + 1);
    float cnt = fmaxf((float)(end - start), 1.f);
    float sum = 0.f;
    for (int f = 0; f < H; ++f)
        sum += pooled[g * H + f] * w_out[f * OUT_DIM + o];
    out[g * OUT_DIM + o] = b_out[o] + sum / cnt;
}

// ---------------- launch ----------------

extern "C" void kernel_launch(void* const* d_in, const int* in_sizes, int n_in,
                              void* d_out, int out_size, void* d_ws, size_t ws_size,
                              hipStream_t stream) {
    const float* x      = (const float*)d_in[0];
    const int*   ei     = (const int*)d_in[1];
    const int*   batch  = (const int*)d_in[2];
    const float* w_rel1 = (const float*)d_in[3];
    const float* w_root1= (const float*)d_in[4];
    const float* b1     = (const float*)d_in[5];
    const float* w_rel  = (const float*)d_in[6];
    const float* w_root = (const float*)d_in[7];
    const float* b      = (const float*)d_in[8];
    const float* w_out  = (const float*)d_in[9];
    const float* b_out  = (const float*)d_in[10];
    float* out = (float*)d_out;

    const int* src = ei;
    const int* dst = ei + N_EDGES;

    float* bufA   = (float*)d_ws;
    float* bufB   = bufA + (size_t)N_NODES * H;
    float* bufAgg = bufB + (size_t)N_NODES * H;
    float* pooled = bufAgg + (size_t)N_NODES * H;

    // ---- layer 1 (3 -> 256) ----
    hipMemsetAsync(bufAgg, 0, (size_t)N_NODES * 3 * sizeof(float), stream);
    scatter3<<<(N_EDGES + 255) / 256, 256, 0, stream>>>(x, src, dst, bufAgg);
    layer1_kernel<<<N_NODES, H, 0, stream>>>(x, bufAgg, w_rel1, w_root1, b1, bufA);

    // ---- layers 2..7 (256 -> 256) ----
    float* cur = bufA;
    float* nxt = bufB;
    for (int l = 0; l < 6; ++l) {
        hipMemsetAsync(bufAgg, 0, (size_t)N_NODES * H * sizeof(float), stream);
        scatterH<<<(N_EDGES * 64) / 256, 256, 0, stream>>>(cur, src, dst, bufAgg);
        dim3 grid((N_NODES + BM - 1) / BM, H / BN);
        gemm_fused<<<grid, 256, 0, stream>>>(bufAgg, cur,
                                             w_rel + (size_t)l * H * H,
                                             w_root + (size_t)l * H * H,
                                             b + (size_t)l * H, nxt, N_NODES);
        float* t = cur; cur = nxt; nxt = t;
    }

    // ---- global mean pool + head ----
    hipMemsetAsync(pooled, 0, G_BATCH * H * sizeof(float), stream);
    pool_partial<<<dim3(G_BATCH, 8), 256, 0, stream>>>(cur, batch, pooled);
    head_kernel<<<G_BATCH, OUT_DIM, 0, stream>>>(pooled, batch, w_out, b_out, out);
}

// Round 2
// 3498.582 us; speedup vs baseline: 5.4037x; 5.4037x over previous
//
#include <hip/hip_runtime.h>

#define N_NODES 50000
#define N_EDGES 800000
#define F_INPUT 3
#define H 256
#define G_BATCH 64
#define OUT_DIM 24

#define SCAN_BLK 256
#define NBLK ((N_NODES + SCAN_BLK - 1) / SCAN_BLK)   // 196

// ---------------- CSR build (edges grouped by dst) ----------------

__global__ void histo_kernel(const int* __restrict__ dst, int* __restrict__ deg) {
    int e = blockIdx.x * blockDim.x + threadIdx.x;
    if (e < N_EDGES) atomicAdd(&deg[dst[e]], 1);
}

// per-chunk exclusive scan (chunk = 256), chunk totals to blockSums
__global__ void scan_block(const int* __restrict__ deg, int* __restrict__ rowptr,
                           int* __restrict__ blockSums) {
    __shared__ int s[SCAN_BLK];
    int idx = blockIdx.x * SCAN_BLK + threadIdx.x;
    int v = (idx < N_NODES) ? deg[idx] : 0;
    s[threadIdx.x] = v;
    __syncthreads();
    // Hillis-Steele inclusive
    for (int off = 1; off < SCAN_BLK; off <<= 1) {
        int t = (threadIdx.x >= off) ? s[threadIdx.x - off] : 0;
        __syncthreads();
        s[threadIdx.x] += t;
        __syncthreads();
    }
    if (idx < N_NODES) rowptr[idx] = s[threadIdx.x] - v;   // exclusive
    if (threadIdx.x == SCAN_BLK - 1) blockSums[blockIdx.x] = s[threadIdx.x];
}

// single-block exclusive scan of the NBLK chunk totals; writes rowptr[N]
__global__ void scan_sums(int* __restrict__ blockSums, int* __restrict__ rowptr) {
    __shared__ int s[SCAN_BLK];
    int v = (threadIdx.x < NBLK) ? blockSums[threadIdx.x] : 0;
    s[threadIdx.x] = v;
    __syncthreads();
    for (int off = 1; off < SCAN_BLK; off <<= 1) {
        int t = (threadIdx.x >= off) ? s[threadIdx.x - off] : 0;
        __syncthreads();
        s[threadIdx.x] += t;
        __syncthreads();
    }
    if (threadIdx.x < NBLK) blockSums[threadIdx.x] = s[threadIdx.x] - v;  // exclusive
    if (threadIdx.x == SCAN_BLK - 1) rowptr[N_NODES] = s[threadIdx.x];    // total = E
}

__global__ void scan_add(int* __restrict__ rowptr, const int* __restrict__ blockSums) {
    int idx = blockIdx.x * blockDim.x + threadIdx.x;
    if (idx < N_NODES) rowptr[idx] += blockSums[idx >> 8];
}

__global__ void fill_csr(const int* __restrict__ src, const int* __restrict__ dst,
                         const int* __restrict__ rowptr, int* __restrict__ cursor,
                         int* __restrict__ csr_src) {
    int e = blockIdx.x * blockDim.x + threadIdx.x;
    if (e >= N_EDGES) return;
    int d = dst[e];
    int pos = atomicAdd(&cursor[d], 1);
    csr_src[rowptr[d] + pos] = src[e];
}

// ---------------- layer 1 (F_IN=3 -> H) ----------------

__global__ void agg3(const float* __restrict__ x, const int* __restrict__ rowptr,
                     const int* __restrict__ csr_src, float* __restrict__ agg) {
    int n = blockIdx.x * blockDim.x + threadIdx.x;
    if (n >= N_NODES) return;
    int beg = rowptr[n], end = rowptr[n + 1];
    float a0 = 0.f, a1 = 0.f, a2 = 0.f;
    for (int i = beg; i < end; ++i) {
        int s = csr_src[i];
        a0 += x[s * 3 + 0];
        a1 += x[s * 3 + 1];
        a2 += x[s * 3 + 2];
    }
    agg[n * 3 + 0] = a0;
    agg[n * 3 + 1] = a1;
    agg[n * 3 + 2] = a2;
}

__global__ void layer1_kernel(const float* __restrict__ x, const float* __restrict__ agg,
                              const float* __restrict__ wr, const float* __restrict__ wro,
                              const float* __restrict__ bias, float* __restrict__ out) {
    int n = blockIdx.x;
    int f = threadIdx.x;
    float a0 = agg[n * 3 + 0], a1 = agg[n * 3 + 1], a2 = agg[n * 3 + 2];
    float x0 = x[n * 3 + 0], x1 = x[n * 3 + 1], x2 = x[n * 3 + 2];
    float v = bias[f];
    v += a0 * wr[0 * H + f] + a1 * wr[1 * H + f] + a2 * wr[2 * H + f];
    v += x0 * wro[0 * H + f] + x1 * wro[1 * H + f] + x2 * wro[2 * H + f];
    out[(size_t)n * H + f] = fmaxf(v, 0.f);
}

// ---------------- gather-aggregate for H=256 (one wave per dst node) ----------------

__global__ __launch_bounds__(256) void aggH(const float* __restrict__ h,
                                            const int* __restrict__ rowptr,
                                            const int* __restrict__ csr_src,
                                            float* __restrict__ agg) {
    int gtid = blockIdx.x * blockDim.x + threadIdx.x;
    int node = gtid >> 6;
    int lane = threadIdx.x & 63;
    if (node >= N_NODES) return;
    int beg = rowptr[node], end = rowptr[node + 1];
    float4 acc = make_float4(0.f, 0.f, 0.f, 0.f);
    for (int i = beg; i < end; ++i) {
        int s = csr_src[i];
        float4 v = *(const float4*)(h + (size_t)s * H + lane * 4);
        acc.x += v.x; acc.y += v.y; acc.z += v.z; acc.w += v.w;
    }
    *(float4*)(agg + (size_t)node * H + lane * 4) = acc;
}

// ---------------- fused dual GEMM: C = relu(Aagg@Wr + Ah@Wo + bias) ----------------

#define BM 64
#define BN 64
#define BK 16

__global__ __launch_bounds__(256) void gemm_fused(
    const float* __restrict__ Aagg, const float* __restrict__ Ah,
    const float* __restrict__ Wr, const float* __restrict__ Wo,
    const float* __restrict__ bias, float* __restrict__ C, int M) {
    __shared__ float sAa[BM][BK + 1];
    __shared__ float sAh[BM][BK + 1];
    __shared__ float sWr[BK][BN];
    __shared__ float sWo[BK][BN];

    int tid = threadIdx.x;
    int tx = tid & 15;
    int ty = tid >> 4;
    int m0 = blockIdx.x * BM;
    int n0 = blockIdx.y * BN;

    float acc[4][4] = {};

    for (int k0 = 0; k0 < H; k0 += BK) {
        for (int i = tid; i < BM * BK; i += 256) {
            int m = i >> 4;
            int k = i & 15;
            int row = m0 + m;
            float va = 0.f, vh = 0.f;
            if (row < M) {
                va = Aagg[(size_t)row * H + k0 + k];
                vh = Ah[(size_t)row * H + k0 + k];
            }
            sAa[m][k] = va;
            sAh[m][k] = vh;
        }
        for (int i = tid; i < BK * BN; i += 256) {
            int k = i >> 6;
            int n = i & 63;
            sWr[k][n] = Wr[(size_t)(k0 + k) * H + n0 + n];
            sWo[k][n] = Wo[(size_t)(k0 + k) * H + n0 + n];
        }
        __syncthreads();

#pragma unroll
        for (int k = 0; k < BK; ++k) {
            float a[4], hh[4], wr[4], wo[4];
#pragma unroll
            for (int i = 0; i < 4; i++) {
                a[i] = sAa[ty * 4 + i][k];
                hh[i] = sAh[ty * 4 + i][k];
            }
#pragma unroll
            for (int j = 0; j < 4; j++) {
                wr[j] = sWr[k][tx * 4 + j];
                wo[j] = sWo[k][tx * 4 + j];
            }
#pragma unroll
            for (int i = 0; i < 4; i++)
#pragma unroll
                for (int j = 0; j < 4; j++)
                    acc[i][j] += a[i] * wr[j] + hh[i] * wo[j];
        }
        __syncthreads();
    }

#pragma unroll
    for (int i = 0; i < 4; i++) {
        int row = m0 + ty * 4 + i;
        if (row >= M) continue;
#pragma unroll
        for (int j = 0; j < 4; j++) {
            int col = n0 + tx * 4 + j;
            float v = acc[i][j] + bias[col];
            C[(size_t)row * H + col] = fmaxf(v, 0.f);
        }
    }
}

// ---------------- pooling ----------------

__device__ __forceinline__ int lowerBound(const int* __restrict__ batch, int val) {
    int lo = 0, hi = N_NODES;
    while (lo < hi) {
        int mid = (lo + hi) >> 1;
        if (batch[mid] < val) lo = mid + 1; else hi = mid;
    }
    return lo;
}

__global__ void pool_partial(const float* __restrict__ h, const int* __restrict__ batch,
                             float* __restrict__ pooled) {
    int g = blockIdx.x;
    int seg = blockIdx.y;
    int f = threadIdx.x;
    int start = lowerBound(batch, g);
    int end = lowerBound(batch, g + 1);
    int len = end - start;
    int s0 = start + (int)((long long)len * seg / 8);
    int s1 = start + (int)((long long)len * (seg + 1) / 8);
    float sum = 0.f;
    for (int n = s0; n < s1; ++n)
        sum += h[(size_t)n * H + f];
    if (s1 > s0)
        atomicAdd(&pooled[g * H + f], sum);
}

__global__ void head_kernel(const float* __restrict__ pooled, const int* __restrict__ batch,
                            const float* __restrict__ w_out, const float* __restrict__ b_out,
                            float* __restrict__ out) {
    int g = blockIdx.x;
    int o = threadIdx.x;
    int start = lowerBound(batch, g);
    int end = lowerBound(batch, g + 1);
    float cnt = fmaxf((float)(end - start), 1.f);
    float sum = 0.f;
    for (int f = 0; f < H; ++f)
        sum += pooled[g * H + f] * w_out[f * OUT_DIM + o];
    out[g * OUT_DIM + o] = b_out[o] + sum / cnt;
}

// ---------------- launch ----------------

extern "C" void kernel_launch(void* const* d_in, const int* in_sizes, int n_in,
                              void* d_out, int out_size, void* d_ws, size_t ws_size,
                              hipStream_t stream) {
    const float* x      = (const float*)d_in[0];
    const int*   ei     = (const int*)d_in[1];
    const int*   batch  = (const int*)d_in[2];
    const float* w_rel1 = (const float*)d_in[3];
    const float* w_root1= (const float*)d_in[4];
    const float* b1     = (const float*)d_in[5];
    const float* w_rel  = (const float*)d_in[6];
    const float* w_root = (const float*)d_in[7];
    const float* b      = (const float*)d_in[8];
    const float* w_out  = (const float*)d_in[9];
    const float* b_out  = (const float*)d_in[10];
    float* out = (float*)d_out;

    const int* src = ei;
    const int* dst = ei + N_EDGES;

    float* bufA   = (float*)d_ws;                         // N*H
    float* bufB   = bufA + (size_t)N_NODES * H;           // N*H
    float* bufAgg = bufB + (size_t)N_NODES * H;           // N*H
    float* pooled = bufAgg + (size_t)N_NODES * H;         // G*H
    int* rowptr    = (int*)(pooled + G_BATCH * H);        // N+1
    int* degcur    = rowptr + (N_NODES + 1);              // N (deg, then cursor)
    int* blockSums = degcur + N_NODES;                    // NBLK
    int* csr_src   = blockSums + SCAN_BLK;                // E

    // ---- build CSR (once per launch, reused by all layers) ----
    hipMemsetAsync(degcur, 0, N_NODES * sizeof(int), stream);
    histo_kernel<<<(N_EDGES + 255) / 256, 256, 0, stream>>>(dst, degcur);
    scan_block<<<NBLK, SCAN_BLK, 0, stream>>>(degcur, rowptr, blockSums);
    scan_sums<<<1, SCAN_BLK, 0, stream>>>(blockSums, rowptr);
    scan_add<<<NBLK, SCAN_BLK, 0, stream>>>(rowptr, blockSums);
    hipMemsetAsync(degcur, 0, N_NODES * sizeof(int), stream);
    fill_csr<<<(N_EDGES + 255) / 256, 256, 0, stream>>>(src, dst, rowptr, degcur, csr_src);

    // ---- layer 1 (3 -> 256) ----
    agg3<<<(N_NODES + 255) / 256, 256, 0, stream>>>(x, rowptr, csr_src, bufAgg);
    layer1_kernel<<<N_NODES, H, 0, stream>>>(x, bufAgg, w_rel1, w_root1, b1, bufA);

    // ---- layers 2..7 (256 -> 256) ----
    float* cur = bufA;
    float* nxt = bufB;
    for (int l = 0; l < 6; ++l) {
        aggH<<<(N_NODES * 64 + 255) / 256, 256, 0, stream>>>(cur, rowptr, csr_src, bufAgg);
        dim3 grid((N_NODES + BM - 1) / BM, H / BN);
        gemm_fused<<<grid, 256, 0, stream>>>(bufAgg, cur,
                                             w_rel + (size_t)l * H * H,
                                             w_root + (size_t)l * H * H,
                                             b + (size_t)l * H, nxt, N_NODES);
        float* t = cur; cur = nxt; nxt = t;
    }

    // ---- global mean pool + head ----
    hipMemsetAsync(pooled, 0, G_BATCH * H * sizeof(float), stream);
    pool_partial<<<dim3(G_BATCH, 8), 256, 0, stream>>>(cur, batch, pooled);
    head_kernel<<<G_BATCH, OUT_DIM, 0, stream>>>(pooled, batch, w_out, b_out, out);
}

// Round 3
// 1071.299 us; speedup vs baseline: 17.6470x; 3.2657x over previous
//
#include <hip/hip_runtime.h>

#define N_NODES 50000
#define N_EDGES 800000
#define F_INPUT 3
#define H 256
#define K_CAT 512
#define G_BATCH 64
#define OUT_DIM 24

#define SCAN_BLK 256
#define NBLK ((N_NODES + SCAN_BLK - 1) / SCAN_BLK)   // 196

typedef __attribute__((ext_vector_type(8))) short short8;
typedef __attribute__((ext_vector_type(4))) float float4v;

__device__ __forceinline__ float bf2f(unsigned short u) {
    return __uint_as_float(((unsigned)u) << 16);
}
__device__ __forceinline__ unsigned short f2bf(float f) {
    unsigned x = __float_as_uint(f);
    unsigned r = (x + 0x7FFFu + ((x >> 16) & 1u)) >> 16;   // RTNE
    return (unsigned short)r;
}

// ---------------- CSR build (edges grouped by dst) ----------------

__global__ void histo_kernel(const int* __restrict__ dst, int* __restrict__ deg) {
    int e = blockIdx.x * blockDim.x + threadIdx.x;
    if (e < N_EDGES) atomicAdd(&deg[dst[e]], 1);
}

__global__ void scan_block(const int* __restrict__ deg, int* __restrict__ rowptr,
                           int* __restrict__ blockSums) {
    __shared__ int s[SCAN_BLK];
    int idx = blockIdx.x * SCAN_BLK + threadIdx.x;
    int v = (idx < N_NODES) ? deg[idx] : 0;
    s[threadIdx.x] = v;
    __syncthreads();
    for (int off = 1; off < SCAN_BLK; off <<= 1) {
        int t = (threadIdx.x >= off) ? s[threadIdx.x - off] : 0;
        __syncthreads();
        s[threadIdx.x] += t;
        __syncthreads();
    }
    if (idx < N_NODES) rowptr[idx] = s[threadIdx.x] - v;
    if (threadIdx.x == SCAN_BLK - 1) blockSums[blockIdx.x] = s[threadIdx.x];
}

__global__ void scan_sums(int* __restrict__ blockSums, int* __restrict__ rowptr) {
    __shared__ int s[SCAN_BLK];
    int v = (threadIdx.x < NBLK) ? blockSums[threadIdx.x] : 0;
    s[threadIdx.x] = v;
    __syncthreads();
    for (int off = 1; off < SCAN_BLK; off <<= 1) {
        int t = (threadIdx.x >= off) ? s[threadIdx.x - off] : 0;
        __syncthreads();
        s[threadIdx.x] += t;
        __syncthreads();
    }
    if (threadIdx.x < NBLK) blockSums[threadIdx.x] = s[threadIdx.x] - v;
    if (threadIdx.x == SCAN_BLK - 1) rowptr[N_NODES] = s[threadIdx.x];
}

__global__ void scan_add(int* __restrict__ rowptr, const int* __restrict__ blockSums) {
    int idx = blockIdx.x * blockDim.x + threadIdx.x;
    if (idx < N_NODES) rowptr[idx] += blockSums[idx >> 8];
}

__global__ void fill_csr(const int* __restrict__ src, const int* __restrict__ dst,
                         const int* __restrict__ rowptr, int* __restrict__ cursor,
                         int* __restrict__ csr_src) {
    int e = blockIdx.x * blockDim.x + threadIdx.x;
    if (e >= N_EDGES) return;
    int d = dst[e];
    int pos = atomicAdd(&cursor[d], 1);
    csr_src[rowptr[d] + pos] = src[e];
}

// ---------------- weight prep: WcatT[l][n][k] = (k<256 ? w_rel[l][k][n] : w_root[l][k-256][n]) ----------------

__global__ void prep_weights(const float* __restrict__ w_rel, const float* __restrict__ w_root,
                             unsigned short* __restrict__ WcatT) {
    // map: thread -> (l, k, n) with n fastest (coalesced reads); scattered bf16 writes
    int idx = blockIdx.x * blockDim.x + threadIdx.x;    // 6*512*256
    if (idx >= 6 * K_CAT * H) return;
    int n = idx & (H - 1);
    int k = (idx >> 8) & (K_CAT - 1);
    int l = idx >> 17;
    float v = (k < H) ? w_rel[(size_t)l * H * H + k * H + n]
                      : w_root[(size_t)l * H * H + (k - H) * H + n];
    WcatT[(size_t)l * H * K_CAT + (size_t)n * K_CAT + k] = f2bf(v);
}

// ---------------- layer 1 (F_IN=3 -> H), fp32 math, bf16 h output into cat ----------------

__global__ void agg3(const float* __restrict__ x, const int* __restrict__ rowptr,
                     const int* __restrict__ csr_src, float* __restrict__ agg) {
    int n = blockIdx.x * blockDim.x + threadIdx.x;
    if (n >= N_NODES) return;
    int beg = rowptr[n], end = rowptr[n + 1];
    float a0 = 0.f, a1 = 0.f, a2 = 0.f;
    for (int i = beg; i < end; ++i) {
        int s = csr_src[i];
        a0 += x[s * 3 + 0];
        a1 += x[s * 3 + 1];
        a2 += x[s * 3 + 2];
    }
    agg[n * 3 + 0] = a0;
    agg[n * 3 + 1] = a1;
    agg[n * 3 + 2] = a2;
}

__global__ void layer1_kernel(const float* __restrict__ x, const float* __restrict__ agg,
                              const float* __restrict__ wr, const float* __restrict__ wro,
                              const float* __restrict__ bias, unsigned short* __restrict__ cat) {
    int n = blockIdx.x;
    int f = threadIdx.x;
    float a0 = agg[n * 3 + 0], a1 = agg[n * 3 + 1], a2 = agg[n * 3 + 2];
    float x0 = x[n * 3 + 0], x1 = x[n * 3 + 1], x2 = x[n * 3 + 2];
    float v = bias[f];
    v += a0 * wr[0 * H + f] + a1 * wr[1 * H + f] + a2 * wr[2 * H + f];
    v += x0 * wro[0 * H + f] + x1 * wro[1 * H + f] + x2 * wro[2 * H + f];
    cat[(size_t)n * K_CAT + H + f] = f2bf(fmaxf(v, 0.f));
}

// ---------------- gather-aggregate (bf16): agg-half of cat <- sum of neighbor h-halves ----------------

__global__ __launch_bounds__(256) void aggH(unsigned short* __restrict__ cat,
                                            const int* __restrict__ rowptr,
                                            const int* __restrict__ csr_src) {
    int gtid = blockIdx.x * blockDim.x + threadIdx.x;
    int node = gtid >> 6;
    int lane = threadIdx.x & 63;
    if (node >= N_NODES) return;
    int beg = rowptr[node], end = rowptr[node + 1];
    float a0 = 0.f, a1 = 0.f, a2 = 0.f, a3 = 0.f;
    for (int i = beg; i < end; ++i) {
        int s = csr_src[i];
        const ushort4 v = *(const ushort4*)(cat + (size_t)s * K_CAT + H + lane * 4);
        a0 += bf2f(v.x); a1 += bf2f(v.y); a2 += bf2f(v.z); a3 += bf2f(v.w);
    }
    ushort4 o;
    o.x = f2bf(a0); o.y = f2bf(a1); o.z = f2bf(a2); o.w = f2bf(a3);
    *(ushort4*)(cat + (size_t)node * K_CAT + lane * 4) = o;
}

// ---------------- MFMA GEMM: C = relu(cat(Mx512) @ WcatT^T + bias) -> h-half of catOut ----------------
// block tile 128x128, 4 waves in 2x2, each wave 64x64 (4x4 of 16x16x32 bf16 mfma)

#define GBM 128
#define GBN 128
#define GBK 32
#define LDT 40   // LDS row stride in shorts (pad 32 -> 40: 80B rows, 2-way bank alias = free)

__global__ __launch_bounds__(256) void gemm_mfma(
    const unsigned short* __restrict__ cat, const unsigned short* __restrict__ WcatT,
    const float* __restrict__ bias, unsigned short* __restrict__ catOut, int M) {
    __shared__ unsigned short sA[GBM][LDT];
    __shared__ unsigned short sB[GBN][LDT];

    const int tid = threadIdx.x;
    const int wave = tid >> 6;
    const int lane = tid & 63;
    const int quad = lane >> 4;
    const int l16 = lane & 15;
    const int wm0 = (wave & 1) * 64;
    const int wn0 = (wave >> 1) * 64;
    const int m0 = blockIdx.x * GBM;
    const int n0 = blockIdx.y * GBN;

    // staging map: uint4 u (8 shorts): row = u>>2, chunk = u&3; threads cover u = tid, tid+256
    const int srow0 = tid >> 2, schunk0 = (tid & 3) * 8;
    const int srow1 = (tid + 256) >> 2, schunk1 = ((tid + 256) & 3) * 8;

    float4v acc[4][4] = {};

    for (int kk = 0; kk < K_CAT; kk += GBK) {
        // stage A (128 rows x 32 k)
        {
            uint4 z = make_uint4(0, 0, 0, 0);
            uint4 v0 = (m0 + srow0 < M)
                ? *(const uint4*)(cat + (size_t)(m0 + srow0) * K_CAT + kk + schunk0) : z;
            uint4 v1 = (m0 + srow1 < M)
                ? *(const uint4*)(cat + (size_t)(m0 + srow1) * K_CAT + kk + schunk1) : z;
            *(uint4*)(&sA[srow0][schunk0]) = v0;
            *(uint4*)(&sA[srow1][schunk1]) = v1;
        }
        // stage B (128 n-rows x 32 k) from WcatT
        {
            uint4 v0 = *(const uint4*)(WcatT + (size_t)(n0 + srow0) * K_CAT + kk + schunk0);
            uint4 v1 = *(const uint4*)(WcatT + (size_t)(n0 + srow1) * K_CAT + kk + schunk1);
            *(uint4*)(&sB[srow0][schunk0]) = v0;
            *(uint4*)(&sB[srow1][schunk1]) = v1;
        }
        __syncthreads();

        short8 a[4], b[4];
#pragma unroll
        for (int i = 0; i < 4; i++) {
            a[i] = *(const short8*)(&sA[wm0 + i * 16 + l16][quad * 8]);
            b[i] = *(const short8*)(&sB[wn0 + i * 16 + l16][quad * 8]);
        }
#pragma unroll
        for (int mi = 0; mi < 4; mi++)
#pragma unroll
            for (int ni = 0; ni < 4; ni++)
                acc[mi][ni] = __builtin_amdgcn_mfma_f32_16x16x32_bf16(a[mi], b[ni], acc[mi][ni], 0, 0, 0);
        __syncthreads();
    }

    // epilogue: bias + relu + bf16 store into h-half of catOut
#pragma unroll
    for (int ni = 0; ni < 4; ni++) {
        int col = n0 + wn0 + ni * 16 + l16;
        float bc = bias[col];
#pragma unroll
        for (int mi = 0; mi < 4; mi++) {
#pragma unroll
            for (int r = 0; r < 4; r++) {
                int row = m0 + wm0 + mi * 16 + quad * 4 + r;
                if (row < M) {
                    float v = acc[mi][ni][r] + bc;
                    catOut[(size_t)row * K_CAT + H + col] = f2bf(fmaxf(v, 0.f));
                }
            }
        }
    }
}

// ---------------- pooling ----------------

__device__ __forceinline__ int lowerBound(const int* __restrict__ batch, int val) {
    int lo = 0, hi = N_NODES;
    while (lo < hi) {
        int mid = (lo + hi) >> 1;
        if (batch[mid] < val) lo = mid + 1; else hi = mid;
    }
    return lo;
}

__global__ void pool_partial(const unsigned short* __restrict__ cat, const int* __restrict__ batch,
                             float* __restrict__ pooled) {
    int g = blockIdx.x;
    int seg = blockIdx.y;
    int f = threadIdx.x;
    int start = lowerBound(batch, g);
    int end = lowerBound(batch, g + 1);
    int len = end - start;
    int s0 = start + (int)((long long)len * seg / 8);
    int s1 = start + (int)((long long)len * (seg + 1) / 8);
    float sum = 0.f;
    for (int n = s0; n < s1; ++n)
        sum += bf2f(cat[(size_t)n * K_CAT + H + f]);
    if (s1 > s0)
        atomicAdd(&pooled[g * H + f], sum);
}

__global__ void head_kernel(const float* __restrict__ pooled, const int* __restrict__ batch,
                            const float* __restrict__ w_out, const float* __restrict__ b_out,
                            float* __restrict__ out) {
    int g = blockIdx.x;
    int o = threadIdx.x;
    int start = lowerBound(batch, g);
    int end = lowerBound(batch, g + 1);
    float cnt = fmaxf((float)(end - start), 1.f);
    float sum = 0.f;
    for (int f = 0; f < H; ++f)
        sum += pooled[g * H + f] * w_out[f * OUT_DIM + o];
    out[g * OUT_DIM + o] = b_out[o] + sum / cnt;
}

// ---------------- launch ----------------

extern "C" void kernel_launch(void* const* d_in, const int* in_sizes, int n_in,
                              void* d_out, int out_size, void* d_ws, size_t ws_size,
                              hipStream_t stream) {
    const float* x      = (const float*)d_in[0];
    const int*   ei     = (const int*)d_in[1];
    const int*   batch  = (const int*)d_in[2];
    const float* w_rel1 = (const float*)d_in[3];
    const float* w_root1= (const float*)d_in[4];
    const float* b1     = (const float*)d_in[5];
    const float* w_rel  = (const float*)d_in[6];
    const float* w_root = (const float*)d_in[7];
    const float* b      = (const float*)d_in[8];
    const float* w_out  = (const float*)d_in[9];
    const float* b_out  = (const float*)d_in[10];
    float* out = (float*)d_out;

    const int* src = ei;
    const int* dst = ei + N_EDGES;

    // workspace layout (16B-aligned chunks)
    unsigned short* catA  = (unsigned short*)d_ws;                       // N*512 bf16
    unsigned short* catB  = catA + (size_t)N_NODES * K_CAT;              // N*512 bf16
    unsigned short* WcatT = catB + (size_t)N_NODES * K_CAT;              // 6*256*512 bf16
    float* agg3buf = (float*)(WcatT + (size_t)6 * H * K_CAT);            // N*3 f32
    float* pooled  = agg3buf + (size_t)N_NODES * 4;                      // G*H f32 (pad agg3 to x4)
    int* rowptr    = (int*)(pooled + G_BATCH * H);                       // N+1
    int* degcur    = rowptr + (N_NODES + 1);                             // N
    int* blockSums = degcur + N_NODES;                                   // 256
    int* csr_src   = blockSums + SCAN_BLK;                               // E

    // ---- build CSR ----
    hipMemsetAsync(degcur, 0, N_NODES * sizeof(int), stream);
    histo_kernel<<<(N_EDGES + 255) / 256, 256, 0, stream>>>(dst, degcur);
    scan_block<<<NBLK, SCAN_BLK, 0, stream>>>(degcur, rowptr, blockSums);
    scan_sums<<<1, SCAN_BLK, 0, stream>>>(blockSums, rowptr);
    scan_add<<<NBLK, SCAN_BLK, 0, stream>>>(rowptr, blockSums);
    hipMemsetAsync(degcur, 0, N_NODES * sizeof(int), stream);
    fill_csr<<<(N_EDGES + 255) / 256, 256, 0, stream>>>(src, dst, rowptr, degcur, csr_src);

    // ---- weights -> bf16 transposed cat ----
    prep_weights<<<(6 * K_CAT * H + 255) / 256, 256, 0, stream>>>(w_rel, w_root, WcatT);

    // ---- layer 1 (3 -> 256), fp32 ----
    agg3<<<(N_NODES + 255) / 256, 256, 0, stream>>>(x, rowptr, csr_src, agg3buf);
    layer1_kernel<<<N_NODES, H, 0, stream>>>(x, agg3buf, w_rel1, w_root1, b1, catA);

    // ---- layers 2..7 (256 -> 256), bf16 MFMA ----
    unsigned short* cur = catA;
    unsigned short* nxt = catB;
    for (int l = 0; l < 6; ++l) {
        aggH<<<(N_NODES * 64 + 255) / 256, 256, 0, stream>>>(cur, rowptr, csr_src);
        dim3 grid((N_NODES + GBM - 1) / GBM, H / GBN);
        gemm_mfma<<<grid, 256, 0, stream>>>(cur, WcatT + (size_t)l * H * K_CAT,
                                            b + (size_t)l * H, nxt, N_NODES);
        unsigned short* t = cur; cur = nxt; nxt = t;
    }

    // ---- global mean pool + head ----
    hipMemsetAsync(pooled, 0, G_BATCH * H * sizeof(float), stream);
    pool_partial<<<dim3(G_BATCH, 8), 256, 0, stream>>>(cur, batch, pooled);
    head_kernel<<<G_BATCH, OUT_DIM, 0, stream>>>(pooled, batch, w_out, b_out, out);
}

// Round 4
// 880.692 us; speedup vs baseline: 21.4664x; 1.2164x over previous
//
#include <hip/hip_runtime.h>

#define N_NODES 50000
#define N_EDGES 800000
#define F_INPUT 3
#define H 256
#define K_CAT 512
#define G_BATCH 64
#define OUT_DIM 24

#define SCAN_BLK 256
#define NBLK ((N_NODES + SCAN_BLK - 1) / SCAN_BLK)   // 196

typedef __attribute__((ext_vector_type(8))) short short8;
typedef __attribute__((ext_vector_type(4))) float float4v;

__device__ __forceinline__ float bf2f(unsigned short u) {
    return __uint_as_float(((unsigned)u) << 16);
}
__device__ __forceinline__ unsigned short f2bf(float f) {
    unsigned x = __float_as_uint(f);
    unsigned r = (x + 0x7FFFu + ((x >> 16) & 1u)) >> 16;   // RTNE
    return (unsigned short)r;
}

// accumulate 8 bf16 (packed in uint4) into acc[8]
__device__ __forceinline__ void acc8(float* acc, const uint4& v) {
    acc[0] += __uint_as_float(v.x << 16);
    acc[1] += __uint_as_float(v.x & 0xffff0000u);
    acc[2] += __uint_as_float(v.y << 16);
    acc[3] += __uint_as_float(v.y & 0xffff0000u);
    acc[4] += __uint_as_float(v.z << 16);
    acc[5] += __uint_as_float(v.z & 0xffff0000u);
    acc[6] += __uint_as_float(v.w << 16);
    acc[7] += __uint_as_float(v.w & 0xffff0000u);
}

// ---------------- CSR build (edges grouped by dst) ----------------

__global__ void histo_kernel(const int* __restrict__ dst, int* __restrict__ deg) {
    int e = blockIdx.x * blockDim.x + threadIdx.x;
    if (e < N_EDGES) atomicAdd(&deg[dst[e]], 1);
}

__global__ void scan_block(const int* __restrict__ deg, int* __restrict__ rowptr,
                           int* __restrict__ blockSums) {
    __shared__ int s[SCAN_BLK];
    int idx = blockIdx.x * SCAN_BLK + threadIdx.x;
    int v = (idx < N_NODES) ? deg[idx] : 0;
    s[threadIdx.x] = v;
    __syncthreads();
    for (int off = 1; off < SCAN_BLK; off <<= 1) {
        int t = (threadIdx.x >= off) ? s[threadIdx.x - off] : 0;
        __syncthreads();
        s[threadIdx.x] += t;
        __syncthreads();
    }
    if (idx < N_NODES) rowptr[idx] = s[threadIdx.x] - v;
    if (threadIdx.x == SCAN_BLK - 1) blockSums[blockIdx.x] = s[threadIdx.x];
}

__global__ void scan_sums(int* __restrict__ blockSums, int* __restrict__ rowptr) {
    __shared__ int s[SCAN_BLK];
    int v = (threadIdx.x < NBLK) ? blockSums[threadIdx.x] : 0;
    s[threadIdx.x] = v;
    __syncthreads();
    for (int off = 1; off < SCAN_BLK; off <<= 1) {
        int t = (threadIdx.x >= off) ? s[threadIdx.x - off] : 0;
        __syncthreads();
        s[threadIdx.x] += t;
        __syncthreads();
    }
    if (threadIdx.x < NBLK) blockSums[threadIdx.x] = s[threadIdx.x] - v;
    if (threadIdx.x == SCAN_BLK - 1) rowptr[N_NODES] = s[threadIdx.x];
}

__global__ void scan_add(int* __restrict__ rowptr, const int* __restrict__ blockSums) {
    int idx = blockIdx.x * blockDim.x + threadIdx.x;
    if (idx < N_NODES) rowptr[idx] += blockSums[idx >> 8];
}

__global__ void fill_csr(const int* __restrict__ src, const int* __restrict__ dst,
                         const int* __restrict__ rowptr, int* __restrict__ cursor,
                         int* __restrict__ csr_src) {
    int e = blockIdx.x * blockDim.x + threadIdx.x;
    if (e >= N_EDGES) return;
    int d = dst[e];
    int pos = atomicAdd(&cursor[d], 1);
    csr_src[rowptr[d] + pos] = src[e];
}

// ---------------- weight prep ----------------

__global__ void prep_weights(const float* __restrict__ w_rel, const float* __restrict__ w_root,
                             unsigned short* __restrict__ WcatT) {
    int idx = blockIdx.x * blockDim.x + threadIdx.x;    // 6*512*256
    if (idx >= 6 * K_CAT * H) return;
    int n = idx & (H - 1);
    int k = (idx >> 8) & (K_CAT - 1);
    int l = idx >> 17;
    float v = (k < H) ? w_rel[(size_t)l * H * H + k * H + n]
                      : w_root[(size_t)l * H * H + (k - H) * H + n];
    WcatT[(size_t)l * H * K_CAT + (size_t)n * K_CAT + k] = f2bf(v);
}

// ---------------- layer 1 (F_IN=3 -> H) ----------------

__global__ void agg3(const float* __restrict__ x, const int* __restrict__ rowptr,
                     const int* __restrict__ csr_src, float* __restrict__ agg) {
    int n = blockIdx.x * blockDim.x + threadIdx.x;
    if (n >= N_NODES) return;
    int beg = rowptr[n], end = rowptr[n + 1];
    float a0 = 0.f, a1 = 0.f, a2 = 0.f;
    for (int i = beg; i < end; ++i) {
        int s = csr_src[i];
        a0 += x[s * 3 + 0];
        a1 += x[s * 3 + 1];
        a2 += x[s * 3 + 2];
    }
    agg[n * 3 + 0] = a0;
    agg[n * 3 + 1] = a1;
    agg[n * 3 + 2] = a2;
}

__global__ void layer1_kernel(const float* __restrict__ x, const float* __restrict__ agg,
                              const float* __restrict__ wr, const float* __restrict__ wro,
                              const float* __restrict__ bias, unsigned short* __restrict__ cat) {
    int n = blockIdx.x;
    int f = threadIdx.x;
    float a0 = agg[n * 3 + 0], a1 = agg[n * 3 + 1], a2 = agg[n * 3 + 2];
    float x0 = x[n * 3 + 0], x1 = x[n * 3 + 1], x2 = x[n * 3 + 2];
    float v = bias[f];
    v += a0 * wr[0 * H + f] + a1 * wr[1 * H + f] + a2 * wr[2 * H + f];
    v += x0 * wro[0 * H + f] + x1 * wro[1 * H + f] + x2 * wro[2 * H + f];
    cat[(size_t)n * K_CAT + H + f] = f2bf(fmaxf(v, 0.f));
}

// ---------------- gather-aggregate (bf16), latency-optimized ----------------
// one wave per node; two 32-lane halves process alternate edges (balanced),
// each lane covers 8 features via uint4 (16B); unroll x2 -> 4 row-gathers in flight.

__global__ __launch_bounds__(256) void aggH(unsigned short* __restrict__ cat,
                                            const int* __restrict__ rowptr,
                                            const int* __restrict__ csr_src) {
    int gtid = blockIdx.x * blockDim.x + threadIdx.x;
    int node = gtid >> 6;
    if (node >= N_NODES) return;
    int lane = threadIdx.x & 63;
    int half = lane >> 5;
    int l32 = lane & 31;
    int beg = rowptr[node], end = rowptr[node + 1];
    float acc[8] = {};
    const unsigned short* hbase = cat + H + l32 * 8;

    int i = beg + half;
    for (; i + 2 < end; i += 4) {
        int s0 = csr_src[i];
        int s1 = csr_src[i + 2];
        uint4 v0 = *(const uint4*)(hbase + (size_t)s0 * K_CAT);
        uint4 v1 = *(const uint4*)(hbase + (size_t)s1 * K_CAT);
        acc8(acc, v0);
        acc8(acc, v1);
    }
    if (i < end) {
        int s0 = csr_src[i];
        uint4 v0 = *(const uint4*)(hbase + (size_t)s0 * K_CAT);
        acc8(acc, v0);
    }

    // cross-half reduce (8 floats)
#pragma unroll
    for (int j = 0; j < 8; j++) acc[j] += __shfl_xor(acc[j], 32, 64);

    if (half == 0) {
        uint4 o;
        o.x = (unsigned)f2bf(acc[0]) | ((unsigned)f2bf(acc[1]) << 16);
        o.y = (unsigned)f2bf(acc[2]) | ((unsigned)f2bf(acc[3]) << 16);
        o.z = (unsigned)f2bf(acc[4]) | ((unsigned)f2bf(acc[5]) << 16);
        o.w = (unsigned)f2bf(acc[6]) | ((unsigned)f2bf(acc[7]) << 16);
        *(uint4*)(cat + (size_t)node * K_CAT + l32 * 8) = o;
    }
}

// ---------------- MFMA GEMM: C = relu(cat(Mx512) @ WcatT^T + bias) -> h-half of catOut ----------------

#define GBM 128
#define GBN 128
#define GBK 32
#define LDT 40

__global__ __launch_bounds__(256) void gemm_mfma(
    const unsigned short* __restrict__ cat, const unsigned short* __restrict__ WcatT,
    const float* __restrict__ bias, unsigned short* __restrict__ catOut, int M) {
    __shared__ unsigned short sA[GBM][LDT];
    __shared__ unsigned short sB[GBN][LDT];

    const int tid = threadIdx.x;
    const int wave = tid >> 6;
    const int lane = tid & 63;
    const int quad = lane >> 4;
    const int l16 = lane & 15;
    const int wm0 = (wave & 1) * 64;
    const int wn0 = (wave >> 1) * 64;
    const int m0 = blockIdx.x * GBM;
    const int n0 = blockIdx.y * GBN;

    const int srow0 = tid >> 2, schunk0 = (tid & 3) * 8;
    const int srow1 = (tid + 256) >> 2, schunk1 = ((tid + 256) & 3) * 8;

    float4v acc[4][4] = {};

    for (int kk = 0; kk < K_CAT; kk += GBK) {
        {
            uint4 z = make_uint4(0, 0, 0, 0);
            uint4 v0 = (m0 + srow0 < M)
                ? *(const uint4*)(cat + (size_t)(m0 + srow0) * K_CAT + kk + schunk0) : z;
            uint4 v1 = (m0 + srow1 < M)
                ? *(const uint4*)(cat + (size_t)(m0 + srow1) * K_CAT + kk + schunk1) : z;
            *(uint4*)(&sA[srow0][schunk0]) = v0;
            *(uint4*)(&sA[srow1][schunk1]) = v1;
        }
        {
            uint4 v0 = *(const uint4*)(WcatT + (size_t)(n0 + srow0) * K_CAT + kk + schunk0);
            uint4 v1 = *(const uint4*)(WcatT + (size_t)(n0 + srow1) * K_CAT + kk + schunk1);
            *(uint4*)(&sB[srow0][schunk0]) = v0;
            *(uint4*)(&sB[srow1][schunk1]) = v1;
        }
        __syncthreads();

        short8 a[4], b[4];
#pragma unroll
        for (int i = 0; i < 4; i++) {
            a[i] = *(const short8*)(&sA[wm0 + i * 16 + l16][quad * 8]);
            b[i] = *(const short8*)(&sB[wn0 + i * 16 + l16][quad * 8]);
        }
#pragma unroll
        for (int mi = 0; mi < 4; mi++)
#pragma unroll
            for (int ni = 0; ni < 4; ni++)
                acc[mi][ni] = __builtin_amdgcn_mfma_f32_16x16x32_bf16(a[mi], b[ni], acc[mi][ni], 0, 0, 0);
        __syncthreads();
    }

#pragma unroll
    for (int ni = 0; ni < 4; ni++) {
        int col = n0 + wn0 + ni * 16 + l16;
        float bc = bias[col];
#pragma unroll
        for (int mi = 0; mi < 4; mi++) {
#pragma unroll
            for (int r = 0; r < 4; r++) {
                int row = m0 + wm0 + mi * 16 + quad * 4 + r;
                if (row < M) {
                    float v = acc[mi][ni][r] + bc;
                    catOut[(size_t)row * K_CAT + H + col] = f2bf(fmaxf(v, 0.f));
                }
            }
        }
    }
}

// ---------------- pooling ----------------

__device__ __forceinline__ int lowerBound(const int* __restrict__ batch, int val) {
    int lo = 0, hi = N_NODES;
    while (lo < hi) {
        int mid = (lo + hi) >> 1;
        if (batch[mid] < val) lo = mid + 1; else hi = mid;
    }
    return lo;
}

__global__ void pool_partial(const unsigned short* __restrict__ cat, const int* __restrict__ batch,
                             float* __restrict__ pooled) {
    int g = blockIdx.x;
    int seg = blockIdx.y;
    int f = threadIdx.x;
    int start = lowerBound(batch, g);
    int end = lowerBound(batch, g + 1);
    int len = end - start;
    int s0 = start + (int)((long long)len * seg / 8);
    int s1 = start + (int)((long long)len * (seg + 1) / 8);
    float sum = 0.f;
    for (int n = s0; n < s1; ++n)
        sum += bf2f(cat[(size_t)n * K_CAT + H + f]);
    if (s1 > s0)
        atomicAdd(&pooled[g * H + f], sum);
}

__global__ void head_kernel(const float* __restrict__ pooled, const int* __restrict__ batch,
                            const float* __restrict__ w_out, const float* __restrict__ b_out,
                            float* __restrict__ out) {
    int g = blockIdx.x;
    int o = threadIdx.x;
    int start = lowerBound(batch, g);
    int end = lowerBound(batch, g + 1);
    float cnt = fmaxf((float)(end - start), 1.f);
    float sum = 0.f;
    for (int f = 0; f < H; ++f)
        sum += pooled[g * H + f] * w_out[f * OUT_DIM + o];
    out[g * OUT_DIM + o] = b_out[o] + sum / cnt;
}

// ---------------- launch ----------------

extern "C" void kernel_launch(void* const* d_in, const int* in_sizes, int n_in,
                              void* d_out, int out_size, void* d_ws, size_t ws_size,
                              hipStream_t stream) {
    const float* x      = (const float*)d_in[0];
    const int*   ei     = (const int*)d_in[1];
    const int*   batch  = (const int*)d_in[2];
    const float* w_rel1 = (const float*)d_in[3];
    const float* w_root1= (const float*)d_in[4];
    const float* b1     = (const float*)d_in[5];
    const float* w_rel  = (const float*)d_in[6];
    const float* w_root = (const float*)d_in[7];
    const float* b      = (const float*)d_in[8];
    const float* w_out  = (const float*)d_in[9];
    const float* b_out  = (const float*)d_in[10];
    float* out = (float*)d_out;

    const int* src = ei;
    const int* dst = ei + N_EDGES;

    unsigned short* catA  = (unsigned short*)d_ws;                       // N*512 bf16
    unsigned short* catB  = catA + (size_t)N_NODES * K_CAT;              // N*512 bf16
    unsigned short* WcatT = catB + (size_t)N_NODES * K_CAT;              // 6*256*512 bf16
    float* agg3buf = (float*)(WcatT + (size_t)6 * H * K_CAT);            // N*4 f32
    float* pooled  = agg3buf + (size_t)N_NODES * 4;                      // G*H f32
    int* rowptr    = (int*)(pooled + G_BATCH * H);                       // N+1
    int* degcur    = rowptr + (N_NODES + 1);                             // N
    int* blockSums = degcur + N_NODES;                                   // 256
    int* csr_src   = blockSums + SCAN_BLK;                               // E

    // ---- build CSR ----
    hipMemsetAsync(degcur, 0, N_NODES * sizeof(int), stream);
    histo_kernel<<<(N_EDGES + 255) / 256, 256, 0, stream>>>(dst, degcur);
    scan_block<<<NBLK, SCAN_BLK, 0, stream>>>(degcur, rowptr, blockSums);
    scan_sums<<<1, SCAN_BLK, 0, stream>>>(blockSums, rowptr);
    scan_add<<<NBLK, SCAN_BLK, 0, stream>>>(rowptr, blockSums);
    hipMemsetAsync(degcur, 0, N_NODES * sizeof(int), stream);
    fill_csr<<<(N_EDGES + 255) / 256, 256, 0, stream>>>(src, dst, rowptr, degcur, csr_src);

    // ---- weights -> bf16 transposed cat ----
    prep_weights<<<(6 * K_CAT * H + 255) / 256, 256, 0, stream>>>(w_rel, w_root, WcatT);

    // ---- layer 1 (3 -> 256), fp32 ----
    agg3<<<(N_NODES + 255) / 256, 256, 0, stream>>>(x, rowptr, csr_src, agg3buf);
    layer1_kernel<<<N_NODES, H, 0, stream>>>(x, agg3buf, w_rel1, w_root1, b1, catA);

    // ---- layers 2..7 (256 -> 256), bf16 MFMA ----
    unsigned short* cur = catA;
    unsigned short* nxt = catB;
    for (int l = 0; l < 6; ++l) {
        aggH<<<(N_NODES * 64 + 255) / 256, 256, 0, stream>>>(cur, rowptr, csr_src);
        dim3 grid((N_NODES + GBM - 1) / GBM, H / GBN);
        gemm_mfma<<<grid, 256, 0, stream>>>(cur, WcatT + (size_t)l * H * K_CAT,
                                            b + (size_t)l * H, nxt, N_NODES);
        unsigned short* t = cur; cur = nxt; nxt = t;
    }

    // ---- global mean pool + head ----
    hipMemsetAsync(pooled, 0, G_BATCH * H * sizeof(float), stream);
    pool_partial<<<dim3(G_BATCH, 8), 256, 0, stream>>>(cur, batch, pooled);
    head_kernel<<<G_BATCH, OUT_DIM, 0, stream>>>(pooled, batch, w_out, b_out, out);
}

// Round 5
// 832.846 us; speedup vs baseline: 22.6996x; 1.0574x over previous
//
#include <hip/hip_runtime.h>

#define N_NODES 50000
#define N_EDGES 800000
#define F_INPUT 3
#define H 256
#define K_CAT 512
#define G_BATCH 64
#define OUT_DIM 24

#define SCAN_BLK 256
#define NBLK ((N_NODES + SCAN_BLK - 1) / SCAN_BLK)   // 196

typedef __attribute__((ext_vector_type(8))) short short8;
typedef __attribute__((ext_vector_type(4))) float float4v;

__device__ __forceinline__ float bf2f(unsigned short u) {
    return __uint_as_float(((unsigned)u) << 16);
}
__device__ __forceinline__ unsigned short f2bf(float f) {
    unsigned x = __float_as_uint(f);
    unsigned r = (x + 0x7FFFu + ((x >> 16) & 1u)) >> 16;   // RTNE
    return (unsigned short)r;
}

__device__ __forceinline__ void acc8(float* acc, const uint4& v) {
    acc[0] += __uint_as_float(v.x << 16);
    acc[1] += __uint_as_float(v.x & 0xffff0000u);
    acc[2] += __uint_as_float(v.y << 16);
    acc[3] += __uint_as_float(v.y & 0xffff0000u);
    acc[4] += __uint_as_float(v.z << 16);
    acc[5] += __uint_as_float(v.z & 0xffff0000u);
    acc[6] += __uint_as_float(v.w << 16);
    acc[7] += __uint_as_float(v.w & 0xffff0000u);
}

// async global->LDS, 16B per lane; lds must be wave-uniform base (HW adds lane*16)
__device__ __forceinline__ void async_copy16(void* lds, const void* g) {
    __builtin_amdgcn_global_load_lds(
        (const __attribute__((address_space(1))) unsigned int*)g,
        (__attribute__((address_space(3))) unsigned int*)lds, 16, 0, 0);
}

// ---------------- CSR build (edges grouped by dst) ----------------

__global__ void histo_kernel(const int* __restrict__ dst, int* __restrict__ deg) {
    int e = blockIdx.x * blockDim.x + threadIdx.x;
    if (e < N_EDGES) atomicAdd(&deg[dst[e]], 1);
}

// reads deg, writes exclusive per-chunk scan, zeroes deg (cursor for fill_csr)
__global__ void scan_block(int* __restrict__ deg, int* __restrict__ rowptr,
                           int* __restrict__ blockSums) {
    __shared__ int s[SCAN_BLK];
    int idx = blockIdx.x * SCAN_BLK + threadIdx.x;
    int v = (idx < N_NODES) ? deg[idx] : 0;
    s[threadIdx.x] = v;
    __syncthreads();
    for (int off = 1; off < SCAN_BLK; off <<= 1) {
        int t = (threadIdx.x >= off) ? s[threadIdx.x - off] : 0;
        __syncthreads();
        s[threadIdx.x] += t;
        __syncthreads();
    }
    if (idx < N_NODES) {
        rowptr[idx] = s[threadIdx.x] - v;
        deg[idx] = 0;
    }
    if (threadIdx.x == SCAN_BLK - 1) blockSums[blockIdx.x] = s[threadIdx.x];
}

__global__ void scan_sums(int* __restrict__ blockSums, int* __restrict__ rowptr) {
    __shared__ int s[SCAN_BLK];
    int v = (threadIdx.x < NBLK) ? blockSums[threadIdx.x] : 0;
    s[threadIdx.x] = v;
    __syncthreads();
    for (int off = 1; off < SCAN_BLK; off <<= 1) {
        int t = (threadIdx.x >= off) ? s[threadIdx.x - off] : 0;
        __syncthreads();
        s[threadIdx.x] += t;
        __syncthreads();
    }
    if (threadIdx.x < NBLK) blockSums[threadIdx.x] = s[threadIdx.x] - v;
    if (threadIdx.x == SCAN_BLK - 1) rowptr[N_NODES] = s[threadIdx.x];
}

__global__ void scan_add(int* __restrict__ rowptr, const int* __restrict__ blockSums) {
    int idx = blockIdx.x * blockDim.x + threadIdx.x;
    if (idx < N_NODES) rowptr[idx] += blockSums[idx >> 8];
}

__global__ void fill_csr(const int* __restrict__ src, const int* __restrict__ dst,
                         const int* __restrict__ rowptr, int* __restrict__ cursor,
                         int* __restrict__ csr_src) {
    int e = blockIdx.x * blockDim.x + threadIdx.x;
    if (e >= N_EDGES) return;
    int d = dst[e];
    int pos = atomicAdd(&cursor[d], 1);
    csr_src[rowptr[d] + pos] = src[e];
}

// ---------------- weight prep ----------------

__global__ void prep_weights(const float* __restrict__ w_rel, const float* __restrict__ w_root,
                             unsigned short* __restrict__ WcatT) {
    int idx = blockIdx.x * blockDim.x + threadIdx.x;    // 6*512*256
    if (idx >= 6 * K_CAT * H) return;
    int n = idx & (H - 1);
    int k = (idx >> 8) & (K_CAT - 1);
    int l = idx >> 17;
    float v = (k < H) ? w_rel[(size_t)l * H * H + k * H + n]
                      : w_root[(size_t)l * H * H + (k - H) * H + n];
    WcatT[(size_t)l * H * K_CAT + (size_t)n * K_CAT + k] = f2bf(v);
}

// ---------------- layer 1 (F_IN=3 -> H) ----------------

__global__ void agg3(const float* __restrict__ x, const int* __restrict__ rowptr,
                     const int* __restrict__ csr_src, float* __restrict__ agg) {
    int n = blockIdx.x * blockDim.x + threadIdx.x;
    if (n >= N_NODES) return;
    int beg = rowptr[n], end = rowptr[n + 1];
    float a0 = 0.f, a1 = 0.f, a2 = 0.f;
    for (int i = beg; i < end; ++i) {
        int s = csr_src[i];
        a0 += x[s * 3 + 0];
        a1 += x[s * 3 + 1];
        a2 += x[s * 3 + 2];
    }
    agg[n * 3 + 0] = a0;
    agg[n * 3 + 1] = a1;
    agg[n * 3 + 2] = a2;
}

__global__ void layer1_kernel(const float* __restrict__ x, const float* __restrict__ agg,
                              const float* __restrict__ wr, const float* __restrict__ wro,
                              const float* __restrict__ bias, unsigned short* __restrict__ cat) {
    int n = blockIdx.x;
    int f = threadIdx.x;
    float a0 = agg[n * 3 + 0], a1 = agg[n * 3 + 1], a2 = agg[n * 3 + 2];
    float x0 = x[n * 3 + 0], x1 = x[n * 3 + 1], x2 = x[n * 3 + 2];
    float v = bias[f];
    v += a0 * wr[0 * H + f] + a1 * wr[1 * H + f] + a2 * wr[2 * H + f];
    v += x0 * wro[0 * H + f] + x1 * wro[1 * H + f] + x2 * wro[2 * H + f];
    cat[(size_t)n * K_CAT + H + f] = f2bf(fmaxf(v, 0.f));
}

// ---------------- gather-aggregate (bf16), unroll x4 ----------------

__global__ __launch_bounds__(256) void aggH(unsigned short* __restrict__ cat,
                                            const int* __restrict__ rowptr,
                                            const int* __restrict__ csr_src) {
    int gtid = blockIdx.x * blockDim.x + threadIdx.x;
    int node = gtid >> 6;
    if (node >= N_NODES) return;
    int lane = threadIdx.x & 63;
    int half = lane >> 5;
    int l32 = lane & 31;
    int beg = rowptr[node], end = rowptr[node + 1];
    float acc[8] = {};
    const unsigned short* hbase = cat + H + l32 * 8;

    int i = beg + half;
    for (; i + 6 < end; i += 8) {
        int s0 = csr_src[i];
        int s1 = csr_src[i + 2];
        int s2 = csr_src[i + 4];
        int s3 = csr_src[i + 6];
        uint4 v0 = *(const uint4*)(hbase + (size_t)s0 * K_CAT);
        uint4 v1 = *(const uint4*)(hbase + (size_t)s1 * K_CAT);
        uint4 v2 = *(const uint4*)(hbase + (size_t)s2 * K_CAT);
        uint4 v3 = *(const uint4*)(hbase + (size_t)s3 * K_CAT);
        acc8(acc, v0);
        acc8(acc, v1);
        acc8(acc, v2);
        acc8(acc, v3);
    }
    for (; i < end; i += 2) {
        int s0 = csr_src[i];
        uint4 v0 = *(const uint4*)(hbase + (size_t)s0 * K_CAT);
        acc8(acc, v0);
    }

#pragma unroll
    for (int j = 0; j < 8; j++) acc[j] += __shfl_xor(acc[j], 32, 64);

    if (half == 0) {
        uint4 o;
        o.x = (unsigned)f2bf(acc[0]) | ((unsigned)f2bf(acc[1]) << 16);
        o.y = (unsigned)f2bf(acc[2]) | ((unsigned)f2bf(acc[3]) << 16);
        o.z = (unsigned)f2bf(acc[4]) | ((unsigned)f2bf(acc[5]) << 16);
        o.w = (unsigned)f2bf(acc[6]) | ((unsigned)f2bf(acc[7]) << 16);
        *(uint4*)(cat + (size_t)node * K_CAT + l32 * 8) = o;
    }
}

// ---------------- MFMA GEMM with global_load_lds staging + XOR swizzle ----------------
// C = relu(cat(Mx512) @ WcatT^T + bias) -> h-half of catOut
// LDS tile: unpadded [128][32] shorts (64B rows); slot (r,c) holds global chunk c^((r>>1)&3)

#define GBM 128
#define GBN 128
#define GBK 32

__global__ __launch_bounds__(256) void gemm_mfma(
    const unsigned short* __restrict__ cat, const unsigned short* __restrict__ WcatT,
    const float* __restrict__ bias, unsigned short* __restrict__ catOut, int M) {
    __shared__ unsigned short sA[GBM][GBK];   // 8 KB
    __shared__ unsigned short sB[GBN][GBK];   // 8 KB

    const int tid = threadIdx.x;
    const int wave = tid >> 6;
    const int lane = tid & 63;
    const int quad = lane >> 4;
    const int l16 = lane & 15;
    const int wm0 = (wave & 1) * 64;
    const int wn0 = (wave >> 1) * 64;
    const int m0 = blockIdx.x * GBM;
    const int n0 = blockIdx.y * GBN;

    // staging: issue j (0,1), wave w: lane covers row (j*4+w)*16 + lane/4,
    // swizzled chunk (lane&3)^((lane>>3)&3); LDS dest = base + (j*4+w)*1024 B (+lane*16 by HW)
    const int r0 = wave * 16 + (lane >> 2);
    const int cks = ((lane & 3) ^ ((lane >> 3) & 3)) * 8;   // shorts
    const unsigned short* Ab0 = cat + (size_t)(m0 + r0) * K_CAT + cks;
    const unsigned short* Ab1 = cat + (size_t)(m0 + r0 + 64) * K_CAT + cks;
    const unsigned short* Bb0 = WcatT + (size_t)(n0 + r0) * K_CAT + cks;
    const unsigned short* Bb1 = WcatT + (size_t)(n0 + r0 + 64) * K_CAT + cks;
    char* sAw = (char*)sA + wave * 1024;
    char* sBw = (char*)sB + wave * 1024;

    // fragment read chunk swizzle: want k-chunk `quad` of row; it sits at chunk quad^((l16>>1)&3)
    const int rq = (quad ^ ((l16 >> 1) & 3)) * 8;   // shorts

    float4v acc[4][4] = {};

    for (int kk = 0; kk < K_CAT; kk += GBK) {
        async_copy16(sAw, Ab0 + kk);
        async_copy16(sAw + 4096, Ab1 + kk);
        async_copy16(sBw, Bb0 + kk);
        async_copy16(sBw + 4096, Bb1 + kk);
        __syncthreads();

        short8 a[4], b[4];
#pragma unroll
        for (int i = 0; i < 4; i++) {
            a[i] = *(const short8*)(&sA[wm0 + i * 16 + l16][rq]);
            b[i] = *(const short8*)(&sB[wn0 + i * 16 + l16][rq]);
        }
#pragma unroll
        for (int mi = 0; mi < 4; mi++)
#pragma unroll
            for (int ni = 0; ni < 4; ni++)
                acc[mi][ni] = __builtin_amdgcn_mfma_f32_16x16x32_bf16(a[mi], b[ni], acc[mi][ni], 0, 0, 0);
        __syncthreads();
    }

#pragma unroll
    for (int ni = 0; ni < 4; ni++) {
        int col = n0 + wn0 + ni * 16 + l16;
        float bc = bias[col];
#pragma unroll
        for (int mi = 0; mi < 4; mi++) {
#pragma unroll
            for (int r = 0; r < 4; r++) {
                int row = m0 + wm0 + mi * 16 + quad * 4 + r;
                if (row < M) {
                    float v = acc[mi][ni][r] + bc;
                    catOut[(size_t)row * K_CAT + H + col] = f2bf(fmaxf(v, 0.f));
                }
            }
        }
    }
}

// ---------------- pooling ----------------

__device__ __forceinline__ int lowerBound(const int* __restrict__ batch, int val) {
    int lo = 0, hi = N_NODES;
    while (lo < hi) {
        int mid = (lo + hi) >> 1;
        if (batch[mid] < val) lo = mid + 1; else hi = mid;
    }
    return lo;
}

__global__ void pool_partial(const unsigned short* __restrict__ cat, const int* __restrict__ batch,
                             float* __restrict__ pooled) {
    int g = blockIdx.x;
    int seg = blockIdx.y;
    int f = threadIdx.x;
    int start = lowerBound(batch, g);
    int end = lowerBound(batch, g + 1);
    int len = end - start;
    int s0 = start + (int)((long long)len * seg / 8);
    int s1 = start + (int)((long long)len * (seg + 1) / 8);
    float sum = 0.f;
    for (int n = s0; n < s1; ++n)
        sum += bf2f(cat[(size_t)n * K_CAT + H + f]);
    if (s1 > s0)
        atomicAdd(&pooled[g * H + f], sum);
}

__global__ void head_kernel(const float* __restrict__ pooled, const int* __restrict__ batch,
                            const float* __restrict__ w_out, const float* __restrict__ b_out,
                            float* __restrict__ out) {
    int g = blockIdx.x;
    int o = threadIdx.x;
    int start = lowerBound(batch, g);
    int end = lowerBound(batch, g + 1);
    float cnt = fmaxf((float)(end - start), 1.f);
    float sum = 0.f;
    for (int f = 0; f < H; ++f)
        sum += pooled[g * H + f] * w_out[f * OUT_DIM + o];
    out[g * OUT_DIM + o] = b_out[o] + sum / cnt;
}

// ---------------- launch ----------------

extern "C" void kernel_launch(void* const* d_in, const int* in_sizes, int n_in,
                              void* d_out, int out_size, void* d_ws, size_t ws_size,
                              hipStream_t stream) {
    const float* x      = (const float*)d_in[0];
    const int*   ei     = (const int*)d_in[1];
    const int*   batch  = (const int*)d_in[2];
    const float* w_rel1 = (const float*)d_in[3];
    const float* w_root1= (const float*)d_in[4];
    const float* b1     = (const float*)d_in[5];
    const float* w_rel  = (const float*)d_in[6];
    const float* w_root = (const float*)d_in[7];
    const float* b      = (const float*)d_in[8];
    const float* w_out  = (const float*)d_in[9];
    const float* b_out  = (const float*)d_in[10];
    float* out = (float*)d_out;

    const int* src = ei;
    const int* dst = ei + N_EDGES;

    unsigned short* catA  = (unsigned short*)d_ws;                       // N*512 bf16
    unsigned short* catB  = catA + (size_t)N_NODES * K_CAT;              // N*512 bf16
    unsigned short* WcatT = catB + (size_t)N_NODES * K_CAT;              // 6*256*512 bf16
    float* agg3buf = (float*)(WcatT + (size_t)6 * H * K_CAT);            // N*4 f32
    float* pooled  = agg3buf + (size_t)N_NODES * 4;                      // G*H f32
    int* rowptr    = (int*)(pooled + G_BATCH * H);                       // N+1
    int* degcur    = rowptr + (N_NODES + 1);                             // N
    int* blockSums = degcur + N_NODES;                                   // 256
    int* csr_src   = blockSums + SCAN_BLK;                               // E

    // ---- build CSR ----
    hipMemsetAsync(degcur, 0, N_NODES * sizeof(int), stream);
    histo_kernel<<<(N_EDGES + 255) / 256, 256, 0, stream>>>(dst, degcur);
    scan_block<<<NBLK, SCAN_BLK, 0, stream>>>(degcur, rowptr, blockSums);
    scan_sums<<<1, SCAN_BLK, 0, stream>>>(blockSums, rowptr);
    scan_add<<<NBLK, SCAN_BLK, 0, stream>>>(rowptr, blockSums);
    fill_csr<<<(N_EDGES + 255) / 256, 256, 0, stream>>>(src, dst, rowptr, degcur, csr_src);

    // ---- weights -> bf16 transposed cat ----
    prep_weights<<<(6 * K_CAT * H + 255) / 256, 256, 0, stream>>>(w_rel, w_root, WcatT);

    // ---- layer 1 (3 -> 256), fp32 ----
    agg3<<<(N_NODES + 255) / 256, 256, 0, stream>>>(x, rowptr, csr_src, agg3buf);
    layer1_kernel<<<N_NODES, H, 0, stream>>>(x, agg3buf, w_rel1, w_root1, b1, catA);

    // ---- layers 2..7 (256 -> 256), bf16 MFMA ----
    unsigned short* cur = catA;
    unsigned short* nxt = catB;
    for (int l = 0; l < 6; ++l) {
        aggH<<<(N_NODES * 64 + 255) / 256, 256, 0, stream>>>(cur, rowptr, csr_src);
        dim3 grid((N_NODES + GBM - 1) / GBM, H / GBN);
        gemm_mfma<<<grid, 256, 0, stream>>>(cur, WcatT + (size_t)l * H * K_CAT,
                                            b + (size_t)l * H, nxt, N_NODES);
        unsigned short* t = cur; cur = nxt; nxt = t;
    }

    // ---- global mean pool + head ----
    hipMemsetAsync(pooled, 0, G_BATCH * H * sizeof(float), stream);
    pool_partial<<<dim3(G_BATCH, 8), 256, 0, stream>>>(cur, batch, pooled);
    head_kernel<<<G_BATCH, OUT_DIM, 0, stream>>>(pooled, batch, w_out, b_out, out);
}

// Round 6
// 698.888 us; speedup vs baseline: 27.0505x; 1.1917x over previous
//
#include <hip/hip_runtime.h>

#define N_NODES 50000
#define MPAD 50048            // 391 * 128, padded M for guard-free GEMM
#define N_EDGES 800000
#define F_INPUT 3
#define H 256
#define K_CAT 512
#define G_BATCH 64
#define OUT_DIM 24

#define SCAN_BLK 256
#define NBLK ((N_NODES + SCAN_BLK - 1) / SCAN_BLK)   // 196

typedef __attribute__((ext_vector_type(8))) short short8;
typedef __attribute__((ext_vector_type(4))) float float4v;

__device__ __forceinline__ float bf2f(unsigned short u) {
    return __uint_as_float(((unsigned)u) << 16);
}
__device__ __forceinline__ unsigned short f2bf(float f) {
    unsigned x = __float_as_uint(f);
    unsigned r = (x + 0x7FFFu + ((x >> 16) & 1u)) >> 16;   // RTNE
    return (unsigned short)r;
}

__device__ __forceinline__ void acc8(float* acc, const uint4& v) {
    acc[0] += __uint_as_float(v.x << 16);
    acc[1] += __uint_as_float(v.x & 0xffff0000u);
    acc[2] += __uint_as_float(v.y << 16);
    acc[3] += __uint_as_float(v.y & 0xffff0000u);
    acc[4] += __uint_as_float(v.z << 16);
    acc[5] += __uint_as_float(v.z & 0xffff0000u);
    acc[6] += __uint_as_float(v.w << 16);
    acc[7] += __uint_as_float(v.w & 0xffff0000u);
}

// async global->LDS, 16B per lane; per-lane source ptr, wave-uniform LDS base (+lane*16 by HW)
__device__ __forceinline__ void async_copy16(void* lds, const void* g) {
    __builtin_amdgcn_global_load_lds(
        (const __attribute__((address_space(1))) unsigned int*)g,
        (__attribute__((address_space(3))) unsigned int*)lds, 16, 0, 0);
}

// ---------------- CSR build (edges grouped by dst) ----------------

// pass 1: degree histogram; also record each edge's rank within its dst bucket
__global__ void histo_kernel(const int* __restrict__ dst, int* __restrict__ deg,
                             int* __restrict__ epos) {
    int e = blockIdx.x * blockDim.x + threadIdx.x;
    if (e < N_EDGES) epos[e] = atomicAdd(&deg[dst[e]], 1);
}

// reads deg, writes exclusive per-chunk scan, zeroes deg
__global__ void scan_block(int* __restrict__ deg, int* __restrict__ rowptr,
                           int* __restrict__ blockSums) {
    __shared__ int s[SCAN_BLK];
    int idx = blockIdx.x * SCAN_BLK + threadIdx.x;
    int v = (idx < N_NODES) ? deg[idx] : 0;
    s[threadIdx.x] = v;
    __syncthreads();
    for (int off = 1; off < SCAN_BLK; off <<= 1) {
        int t = (threadIdx.x >= off) ? s[threadIdx.x - off] : 0;
        __syncthreads();
        s[threadIdx.x] += t;
        __syncthreads();
    }
    if (idx < N_NODES) {
        rowptr[idx] = s[threadIdx.x] - v;
        deg[idx] = 0;
    }
    if (threadIdx.x == SCAN_BLK - 1) blockSums[blockIdx.x] = s[threadIdx.x];
}

__global__ void scan_sums(int* __restrict__ blockSums, int* __restrict__ rowptr) {
    __shared__ int s[SCAN_BLK];
    int v = (threadIdx.x < NBLK) ? blockSums[threadIdx.x] : 0;
    s[threadIdx.x] = v;
    __syncthreads();
    for (int off = 1; off < SCAN_BLK; off <<= 1) {
        int t = (threadIdx.x >= off) ? s[threadIdx.x - off] : 0;
        __syncthreads();
        s[threadIdx.x] += t;
        __syncthreads();
    }
    if (threadIdx.x < NBLK) blockSums[threadIdx.x] = s[threadIdx.x] - v;
    if (threadIdx.x == SCAN_BLK - 1) rowptr[N_NODES] = s[threadIdx.x];
}

__global__ void scan_add(int* __restrict__ rowptr, const int* __restrict__ blockSums) {
    int idx = blockIdx.x * blockDim.x + threadIdx.x;
    if (idx < N_NODES) rowptr[idx] += blockSums[idx >> 8];
}

// pass 2: atomic-free scatter using precomputed ranks
__global__ void fill_csr(const int* __restrict__ src, const int* __restrict__ dst,
                         const int* __restrict__ rowptr, const int* __restrict__ epos,
                         int* __restrict__ csr_src) {
    int e = blockIdx.x * blockDim.x + threadIdx.x;
    if (e >= N_EDGES) return;
    csr_src[rowptr[dst[e]] + epos[e]] = src[e];
}

// ---------------- weight prep ----------------

__global__ void prep_weights(const float* __restrict__ w_rel, const float* __restrict__ w_root,
                             unsigned short* __restrict__ WcatT) {
    int idx = blockIdx.x * blockDim.x + threadIdx.x;    // 6*512*256
    if (idx >= 6 * K_CAT * H) return;
    int n = idx & (H - 1);
    int k = (idx >> 8) & (K_CAT - 1);
    int l = idx >> 17;
    float v = (k < H) ? w_rel[(size_t)l * H * H + k * H + n]
                      : w_root[(size_t)l * H * H + (k - H) * H + n];
    WcatT[(size_t)l * H * K_CAT + (size_t)n * K_CAT + k] = f2bf(v);
}

// ---------------- layer 1 (F_IN=3 -> H) ----------------

__global__ void agg3(const float* __restrict__ x, const int* __restrict__ rowptr,
                     const int* __restrict__ csr_src, float* __restrict__ agg) {
    int n = blockIdx.x * blockDim.x + threadIdx.x;
    if (n >= N_NODES) return;
    int beg = rowptr[n], end = rowptr[n + 1];
    float a0 = 0.f, a1 = 0.f, a2 = 0.f;
    for (int i = beg; i < end; ++i) {
        int s = csr_src[i];
        a0 += x[s * 3 + 0];
        a1 += x[s * 3 + 1];
        a2 += x[s * 3 + 2];
    }
    agg[n * 3 + 0] = a0;
    agg[n * 3 + 1] = a1;
    agg[n * 3 + 2] = a2;
}

__global__ void layer1_kernel(const float* __restrict__ x, const float* __restrict__ agg,
                              const float* __restrict__ wr, const float* __restrict__ wro,
                              const float* __restrict__ bias, unsigned short* __restrict__ cat) {
    int n = blockIdx.x;
    int f = threadIdx.x;
    float a0 = agg[n * 3 + 0], a1 = agg[n * 3 + 1], a2 = agg[n * 3 + 2];
    float x0 = x[n * 3 + 0], x1 = x[n * 3 + 1], x2 = x[n * 3 + 2];
    float v = bias[f];
    v += a0 * wr[0 * H + f] + a1 * wr[1 * H + f] + a2 * wr[2 * H + f];
    v += x0 * wro[0 * H + f] + x1 * wro[1 * H + f] + x2 * wro[2 * H + f];
    cat[(size_t)n * K_CAT + H + f] = f2bf(fmaxf(v, 0.f));
}

// ---------------- gather-aggregate (bf16), unroll x4 ----------------

__global__ __launch_bounds__(256) void aggH(unsigned short* __restrict__ cat,
                                            const int* __restrict__ rowptr,
                                            const int* __restrict__ csr_src) {
    int gtid = blockIdx.x * blockDim.x + threadIdx.x;
    int node = gtid >> 6;
    if (node >= N_NODES) return;
    int lane = threadIdx.x & 63;
    int half = lane >> 5;
    int l32 = lane & 31;
    int beg = rowptr[node], end = rowptr[node + 1];
    float acc[8] = {};
    const unsigned short* hbase = cat + H + l32 * 8;

    int i = beg + half;
    for (; i + 6 < end; i += 8) {
        int s0 = csr_src[i];
        int s1 = csr_src[i + 2];
        int s2 = csr_src[i + 4];
        int s3 = csr_src[i + 6];
        uint4 v0 = *(const uint4*)(hbase + (size_t)s0 * K_CAT);
        uint4 v1 = *(const uint4*)(hbase + (size_t)s1 * K_CAT);
        uint4 v2 = *(const uint4*)(hbase + (size_t)s2 * K_CAT);
        uint4 v3 = *(const uint4*)(hbase + (size_t)s3 * K_CAT);
        acc8(acc, v0);
        acc8(acc, v1);
        acc8(acc, v2);
        acc8(acc, v3);
    }
    for (; i < end; i += 2) {
        int s0 = csr_src[i];
        uint4 v0 = *(const uint4*)(hbase + (size_t)s0 * K_CAT);
        acc8(acc, v0);
    }

#pragma unroll
    for (int j = 0; j < 8; j++) acc[j] += __shfl_xor(acc[j], 32, 64);

    if (half == 0) {
        uint4 o;
        o.x = (unsigned)f2bf(acc[0]) | ((unsigned)f2bf(acc[1]) << 16);
        o.y = (unsigned)f2bf(acc[2]) | ((unsigned)f2bf(acc[3]) << 16);
        o.z = (unsigned)f2bf(acc[4]) | ((unsigned)f2bf(acc[5]) << 16);
        o.w = (unsigned)f2bf(acc[6]) | ((unsigned)f2bf(acc[7]) << 16);
        *(uint4*)(cat + (size_t)node * K_CAT + l32 * 8) = o;
    }
}

// ---------------- MFMA GEMM, GBK=64, guard-free (M padded to 50048) ----------------
// C = relu(cat(MPADx512) @ WcatT^T + bias) -> h-half of catOut
// LDS [128][64] shorts unpadded; slot (r,c16) holds global 16B-chunk c16^(r&7)

#define GBM 128
#define GBN 128
#define GBK 64

__global__ __launch_bounds__(256) void gemm_mfma(
    const unsigned short* __restrict__ cat, const unsigned short* __restrict__ WcatT,
    const float* __restrict__ bias, unsigned short* __restrict__ catOut) {
    __shared__ unsigned short sA[GBM][GBK];   // 16 KB
    __shared__ unsigned short sB[GBN][GBK];   // 16 KB

    const int tid = threadIdx.x;
    const int wave = tid >> 6;
    const int lane = tid & 63;
    const int quad = lane >> 4;
    const int l16 = lane & 15;
    const int wm0 = (wave & 1) * 64;
    const int wn0 = (wave >> 1) * 64;
    const int m0 = blockIdx.x * GBM;
    const int n0 = blockIdx.y * GBN;

    // staging: issue q = wave*4+j covers rows q*8..q*8+7 (1 KB); lane: row_off=lane>>3,
    // stored slot lane&7 must hold global chunk (lane&7)^(row&7) = (lane&7)^(lane>>3)
    const int rowoff = lane >> 3;
    const int schunk = ((lane & 7) ^ rowoff) * 8;   // shorts
    const unsigned short* Asrc[4];
    const unsigned short* Bsrc[4];
#pragma unroll
    for (int j = 0; j < 4; j++) {
        int q = wave * 4 + j;
        Asrc[j] = cat + (size_t)(m0 + q * 8 + rowoff) * K_CAT + schunk;
        Bsrc[j] = WcatT + (size_t)(n0 + q * 8 + rowoff) * K_CAT + schunk;
    }

    // fragment read: logical chunk c at row r sits at slot c^(r&7); row&7 == l16&7
    const int sw = l16 & 7;
    const int ca0 = (quad ^ sw) * 8;         // sub-k 0: logical chunk quad
    const int ca1 = ((4 + quad) ^ sw) * 8;   // sub-k 1: logical chunk 4+quad

    float4v acc[4][4] = {};

    for (int kk = 0; kk < K_CAT; kk += GBK) {
#pragma unroll
        for (int j = 0; j < 4; j++) {
            char* da = (char*)sA + (wave * 4 + j) * 1024;
            char* db = (char*)sB + (wave * 4 + j) * 1024;
            async_copy16(da, Asrc[j] + kk);
            async_copy16(db, Bsrc[j] + kk);
        }
        __syncthreads();

        short8 a[4][2], b[4][2];
#pragma unroll
        for (int i = 0; i < 4; i++) {
            const unsigned short* ra = &sA[wm0 + i * 16 + l16][0];
            const unsigned short* rb = &sB[wn0 + i * 16 + l16][0];
            a[i][0] = *(const short8*)(ra + ca0);
            a[i][1] = *(const short8*)(ra + ca1);
            b[i][0] = *(const short8*)(rb + ca0);
            b[i][1] = *(const short8*)(rb + ca1);
        }
#pragma unroll
        for (int sub = 0; sub < 2; sub++)
#pragma unroll
            for (int mi = 0; mi < 4; mi++)
#pragma unroll
                for (int ni = 0; ni < 4; ni++)
                    acc[mi][ni] = __builtin_amdgcn_mfma_f32_16x16x32_bf16(
                        a[mi][sub], b[ni][sub], acc[mi][ni], 0, 0, 0);
        __syncthreads();
    }

#pragma unroll
    for (int ni = 0; ni < 4; ni++) {
        int col = n0 + wn0 + ni * 16 + l16;
        float bc = bias[col];
#pragma unroll
        for (int mi = 0; mi < 4; mi++) {
            int row = m0 + wm0 + mi * 16 + quad * 4;
#pragma unroll
            for (int r = 0; r < 4; r++) {
                float v = acc[mi][ni][r] + bc;
                catOut[(size_t)(row + r) * K_CAT + H + col] = f2bf(fmaxf(v, 0.f));
            }
        }
    }
}

// ---------------- pooling ----------------

__device__ __forceinline__ int lowerBound(const int* __restrict__ batch, int val) {
    int lo = 0, hi = N_NODES;
    while (lo < hi) {
        int mid = (lo + hi) >> 1;
        if (batch[mid] < val) lo = mid + 1; else hi = mid;
    }
    return lo;
}

__global__ void pool_partial(const unsigned short* __restrict__ cat, const int* __restrict__ batch,
                             float* __restrict__ pooled) {
    int g = blockIdx.x;
    int seg = blockIdx.y;
    int f = threadIdx.x;
    int start = lowerBound(batch, g);
    int end = lowerBound(batch, g + 1);
    int len = end - start;
    int s0 = start + (int)((long long)len * seg / 8);
    int s1 = start + (int)((long long)len * (seg + 1) / 8);
    float sum = 0.f;
    for (int n = s0; n < s1; ++n)
        sum += bf2f(cat[(size_t)n * K_CAT + H + f]);
    if (s1 > s0)
        atomicAdd(&pooled[g * H + f], sum);
}

__global__ void head_kernel(const float* __restrict__ pooled, const int* __restrict__ batch,
                            const float* __restrict__ w_out, const float* __restrict__ b_out,
                            float* __restrict__ out) {
    int g = blockIdx.x;
    int o = threadIdx.x;
    int start = lowerBound(batch, g);
    int end = lowerBound(batch, g + 1);
    float cnt = fmaxf((float)(end - start), 1.f);
    float sum = 0.f;
    for (int f = 0; f < H; ++f)
        sum += pooled[g * H + f] * w_out[f * OUT_DIM + o];
    out[g * OUT_DIM + o] = b_out[o] + sum / cnt;
}

// ---------------- launch ----------------

extern "C" void kernel_launch(void* const* d_in, const int* in_sizes, int n_in,
                              void* d_out, int out_size, void* d_ws, size_t ws_size,
                              hipStream_t stream) {
    const float* x      = (const float*)d_in[0];
    const int*   ei     = (const int*)d_in[1];
    const int*   batch  = (const int*)d_in[2];
    const float* w_rel1 = (const float*)d_in[3];
    const float* w_root1= (const float*)d_in[4];
    const float* b1     = (const float*)d_in[5];
    const float* w_rel  = (const float*)d_in[6];
    const float* w_root = (const float*)d_in[7];
    const float* b      = (const float*)d_in[8];
    const float* w_out  = (const float*)d_in[9];
    const float* b_out  = (const float*)d_in[10];
    float* out = (float*)d_out;

    const int* src = ei;
    const int* dst = ei + N_EDGES;

    unsigned short* catA  = (unsigned short*)d_ws;                       // MPAD*512 bf16
    unsigned short* catB  = catA + (size_t)MPAD * K_CAT;                 // MPAD*512 bf16
    unsigned short* WcatT = catB + (size_t)MPAD * K_CAT;                 // 6*256*512 bf16
    float* agg3buf = (float*)(WcatT + (size_t)6 * H * K_CAT);            // N*4 f32
    float* pooled  = agg3buf + (size_t)N_NODES * 4;                      // G*H f32
    int* rowptr    = (int*)(pooled + G_BATCH * H);                       // N+1
    int* degcur    = rowptr + (N_NODES + 1);                             // N
    int* blockSums = degcur + N_NODES;                                   // 256
    int* csr_src   = blockSums + SCAN_BLK;                               // E
    int* epos      = csr_src + N_EDGES;                                  // E

    // ---- build CSR ----
    hipMemsetAsync(degcur, 0, N_NODES * sizeof(int), stream);
    histo_kernel<<<(N_EDGES + 255) / 256, 256, 0, stream>>>(dst, degcur, epos);
    scan_block<<<NBLK, SCAN_BLK, 0, stream>>>(degcur, rowptr, blockSums);
    scan_sums<<<1, SCAN_BLK, 0, stream>>>(blockSums, rowptr);
    scan_add<<<NBLK, SCAN_BLK, 0, stream>>>(rowptr, blockSums);
    fill_csr<<<(N_EDGES + 255) / 256, 256, 0, stream>>>(src, dst, rowptr, epos, csr_src);

    // ---- weights -> bf16 transposed cat ----
    prep_weights<<<(6 * K_CAT * H + 255) / 256, 256, 0, stream>>>(w_rel, w_root, WcatT);

    // ---- layer 1 (3 -> 256), fp32 ----
    agg3<<<(N_NODES + 255) / 256, 256, 0, stream>>>(x, rowptr, csr_src, agg3buf);
    layer1_kernel<<<N_NODES, H, 0, stream>>>(x, agg3buf, w_rel1, w_root1, b1, catA);

    // ---- layers 2..7 (256 -> 256), bf16 MFMA ----
    unsigned short* cur = catA;
    unsigned short* nxt = catB;
    for (int l = 0; l < 6; ++l) {
        aggH<<<(N_NODES * 64 + 255) / 256, 256, 0, stream>>>(cur, rowptr, csr_src);
        dim3 grid(MPAD / GBM, H / GBN);
        gemm_mfma<<<grid, 256, 0, stream>>>(cur, WcatT + (size_t)l * H * K_CAT,
                                            b + (size_t)l * H, nxt);
        unsigned short* t = cur; cur = nxt; nxt = t;
    }

    // ---- global mean pool + head ----
    hipMemsetAsync(pooled, 0, G_BATCH * H * sizeof(float), stream);
    pool_partial<<<dim3(G_BATCH, 8), 256, 0, stream>>>(cur, batch, pooled);
    head_kernel<<<G_BATCH, OUT_DIM, 0, stream>>>(pooled, batch, w_out, b_out, out);
}

// Round 7
// 684.343 us; speedup vs baseline: 27.6254x; 1.0213x over previous
//
#include <hip/hip_runtime.h>

#define N_NODES 50000
#define MPAD 50048            // 391 * 128, padded M for guard-free GEMM
#define N_EDGES 800000
#define F_INPUT 3
#define H 256
#define K_CAT 512
#define G_BATCH 64
#define OUT_DIM 24

#define SCAN_BLK 256
#define NBLK ((N_NODES + SCAN_BLK - 1) / SCAN_BLK)   // 196

typedef __attribute__((ext_vector_type(8))) short short8;
typedef __attribute__((ext_vector_type(4))) float float4v;

__device__ __forceinline__ float bf2f(unsigned short u) {
    return __uint_as_float(((unsigned)u) << 16);
}
__device__ __forceinline__ unsigned short f2bf(float f) {
    unsigned x = __float_as_uint(f);
    unsigned r = (x + 0x7FFFu + ((x >> 16) & 1u)) >> 16;   // RTNE
    return (unsigned short)r;
}

// async global->LDS, 16B per lane; per-lane source ptr, wave-uniform LDS base (+lane*16 by HW)
__device__ __forceinline__ void async_copy16(void* lds, const void* g) {
    __builtin_amdgcn_global_load_lds(
        (const __attribute__((address_space(1))) unsigned int*)g,
        (__attribute__((address_space(3))) unsigned int*)lds, 16, 0, 0);
}

// ---------------- CSR build (edges grouped by dst) ----------------

__global__ void histo_kernel(const int* __restrict__ dst, int* __restrict__ deg,
                             int* __restrict__ epos) {
    int e = blockIdx.x * blockDim.x + threadIdx.x;
    if (e < N_EDGES) epos[e] = atomicAdd(&deg[dst[e]], 1);
}

__global__ void scan_block(int* __restrict__ deg, int* __restrict__ rowptr,
                           int* __restrict__ blockSums) {
    __shared__ int s[SCAN_BLK];
    int idx = blockIdx.x * SCAN_BLK + threadIdx.x;
    int v = (idx < N_NODES) ? deg[idx] : 0;
    s[threadIdx.x] = v;
    __syncthreads();
    for (int off = 1; off < SCAN_BLK; off <<= 1) {
        int t = (threadIdx.x >= off) ? s[threadIdx.x - off] : 0;
        __syncthreads();
        s[threadIdx.x] += t;
        __syncthreads();
    }
    if (idx < N_NODES) {
        rowptr[idx] = s[threadIdx.x] - v;
        deg[idx] = 0;
    }
    if (threadIdx.x == SCAN_BLK - 1) blockSums[blockIdx.x] = s[threadIdx.x];
}

__global__ void scan_sums(int* __restrict__ blockSums, int* __restrict__ rowptr) {
    __shared__ int s[SCAN_BLK];
    int v = (threadIdx.x < NBLK) ? blockSums[threadIdx.x] : 0;
    s[threadIdx.x] = v;
    __syncthreads();
    for (int off = 1; off < SCAN_BLK; off <<= 1) {
        int t = (threadIdx.x >= off) ? s[threadIdx.x - off] : 0;
        __syncthreads();
        s[threadIdx.x] += t;
        __syncthreads();
    }
    if (threadIdx.x < NBLK) blockSums[threadIdx.x] = s[threadIdx.x] - v;
    if (threadIdx.x == SCAN_BLK - 1) rowptr[N_NODES] = s[threadIdx.x];
}

__global__ void scan_add(int* __restrict__ rowptr, const int* __restrict__ blockSums) {
    int idx = blockIdx.x * blockDim.x + threadIdx.x;
    if (idx < N_NODES) rowptr[idx] += blockSums[idx >> 8];
}

__global__ void fill_csr(const int* __restrict__ src, const int* __restrict__ dst,
                         const int* __restrict__ rowptr, const int* __restrict__ epos,
                         int* __restrict__ csr_src) {
    int e = blockIdx.x * blockDim.x + threadIdx.x;
    if (e >= N_EDGES) return;
    csr_src[rowptr[dst[e]] + epos[e]] = src[e];
}

// ---------------- weight prep ----------------

__global__ void prep_weights(const float* __restrict__ w_rel, const float* __restrict__ w_root,
                             unsigned short* __restrict__ WcatT) {
    int idx = blockIdx.x * blockDim.x + threadIdx.x;    // 6*512*256
    if (idx >= 6 * K_CAT * H) return;
    int n = idx & (H - 1);
    int k = (idx >> 8) & (K_CAT - 1);
    int l = idx >> 17;
    float v = (k < H) ? w_rel[(size_t)l * H * H + k * H + n]
                      : w_root[(size_t)l * H * H + (k - H) * H + n];
    WcatT[(size_t)l * H * K_CAT + (size_t)n * K_CAT + k] = f2bf(v);
}

// ---------------- layer 1 (F_IN=3 -> H) ----------------

__global__ void agg3(const float* __restrict__ x, const int* __restrict__ rowptr,
                     const int* __restrict__ csr_src, float* __restrict__ agg) {
    int n = blockIdx.x * blockDim.x + threadIdx.x;
    if (n >= N_NODES) return;
    int beg = rowptr[n], end = rowptr[n + 1];
    float a0 = 0.f, a1 = 0.f, a2 = 0.f;
    for (int i = beg; i < end; ++i) {
        int s = csr_src[i];
        a0 += x[s * 3 + 0];
        a1 += x[s * 3 + 1];
        a2 += x[s * 3 + 2];
    }
    agg[n * 3 + 0] = a0;
    agg[n * 3 + 1] = a1;
    agg[n * 3 + 2] = a2;
}

__global__ void layer1_kernel(const float* __restrict__ x, const float* __restrict__ agg,
                              const float* __restrict__ wr, const float* __restrict__ wro,
                              const float* __restrict__ bias, unsigned short* __restrict__ cat) {
    int n = blockIdx.x;
    int f = threadIdx.x;
    float a0 = agg[n * 3 + 0], a1 = agg[n * 3 + 1], a2 = agg[n * 3 + 2];
    float x0 = x[n * 3 + 0], x1 = x[n * 3 + 1], x2 = x[n * 3 + 2];
    float v = bias[f];
    v += a0 * wr[0 * H + f] + a1 * wr[1 * H + f] + a2 * wr[2 * H + f];
    v += x0 * wro[0 * H + f] + x1 * wro[1 * H + f] + x2 * wro[2 * H + f];
    cat[(size_t)n * K_CAT + H + f] = f2bf(fmaxf(v, 0.f));
}

// ---------------- per-node uint8 quantization of h (one wave per node) ----------------
// h >= 0 (ReLU). q = round(h * 255 / rowmax), scale = rowmax/255.

__global__ __launch_bounds__(256) void quantH(const unsigned short* __restrict__ cat,
                                              unsigned char* __restrict__ h8,
                                              float* __restrict__ hscale) {
    int gtid = blockIdx.x * blockDim.x + threadIdx.x;
    int node = gtid >> 6;
    if (node >= N_NODES) return;
    int lane = threadIdx.x & 63;
    const unsigned short* hrow = cat + (size_t)node * K_CAT + H;
    uint2 v = *(const uint2*)(hrow + lane * 4);
    float f0 = __uint_as_float(v.x << 16);
    float f1 = __uint_as_float(v.x & 0xffff0000u);
    float f2 = __uint_as_float(v.y << 16);
    float f3 = __uint_as_float(v.y & 0xffff0000u);
    float m = fmaxf(fmaxf(f0, f1), fmaxf(f2, f3));   // h >= 0
#pragma unroll
    for (int off = 1; off < 64; off <<= 1)
        m = fmaxf(m, __shfl_xor(m, off, 64));
    m = fmaxf(m, 1e-30f);
    float inv = 255.f / m;
    unsigned q0 = (unsigned)(int)rintf(f0 * inv);
    unsigned q1 = (unsigned)(int)rintf(f1 * inv);
    unsigned q2 = (unsigned)(int)rintf(f2 * inv);
    unsigned q3 = (unsigned)(int)rintf(f3 * inv);
    unsigned packed = q0 | (q1 << 8) | (q2 << 16) | (q3 << 24);
    *(unsigned*)(h8 + (size_t)node * H + lane * 4) = packed;
    if (lane == 0) hscale[node] = m / 255.f;
}

// ---------------- gather-aggregate from int8 rows ----------------
// one wave per node; 4 lanes-groups of 16 cover 4 edges per load instruction;
// lane group fl covers features fl*16..fl*16+15 (16 B of the 256 B int8 row).

__global__ __launch_bounds__(256) void aggH(unsigned short* __restrict__ cat,
                                            const unsigned char* __restrict__ h8,
                                            const float* __restrict__ hscale,
                                            const int* __restrict__ rowptr,
                                            const int* __restrict__ csr_src) {
    int gtid = blockIdx.x * blockDim.x + threadIdx.x;
    int node = gtid >> 6;
    if (node >= N_NODES) return;
    int lane = threadIdx.x & 63;
    int sub = lane >> 4;        // edge slot 0..3
    int fl = lane & 15;         // feature group
    int beg = rowptr[node], end = rowptr[node + 1];
    float acc[16] = {};
    const unsigned char* base = h8 + fl * 16;

    for (int i = beg; i < end; i += 4) {
        int idx = i + sub;
        int clamped = idx < end ? idx : end - 1;
        int s = csr_src[clamped];
        float sc = (idx < end) ? hscale[s] : 0.f;
        uint4 q = *(const uint4*)(base + (size_t)s * H);
        acc[0]  = fmaf((float)(q.x & 0xffu), sc, acc[0]);
        acc[1]  = fmaf((float)((q.x >> 8) & 0xffu), sc, acc[1]);
        acc[2]  = fmaf((float)((q.x >> 16) & 0xffu), sc, acc[2]);
        acc[3]  = fmaf((float)(q.x >> 24), sc, acc[3]);
        acc[4]  = fmaf((float)(q.y & 0xffu), sc, acc[4]);
        acc[5]  = fmaf((float)((q.y >> 8) & 0xffu), sc, acc[5]);
        acc[6]  = fmaf((float)((q.y >> 16) & 0xffu), sc, acc[6]);
        acc[7]  = fmaf((float)(q.y >> 24), sc, acc[7]);
        acc[8]  = fmaf((float)(q.z & 0xffu), sc, acc[8]);
        acc[9]  = fmaf((float)((q.z >> 8) & 0xffu), sc, acc[9]);
        acc[10] = fmaf((float)((q.z >> 16) & 0xffu), sc, acc[10]);
        acc[11] = fmaf((float)(q.z >> 24), sc, acc[11]);
        acc[12] = fmaf((float)(q.w & 0xffu), sc, acc[12]);
        acc[13] = fmaf((float)((q.w >> 8) & 0xffu), sc, acc[13]);
        acc[14] = fmaf((float)((q.w >> 16) & 0xffu), sc, acc[14]);
        acc[15] = fmaf((float)(q.w >> 24), sc, acc[15]);
    }

    // combine the 4 edge slots (xor 16 and 32 flip the sub bits, fl preserved)
#pragma unroll
    for (int j = 0; j < 16; j++) {
        acc[j] += __shfl_xor(acc[j], 16, 64);
        acc[j] += __shfl_xor(acc[j], 32, 64);
    }

    if (sub == 0) {
        unsigned short* o = cat + (size_t)node * K_CAT + fl * 16;
        uint4 p0, p1;
        p0.x = (unsigned)f2bf(acc[0])  | ((unsigned)f2bf(acc[1]) << 16);
        p0.y = (unsigned)f2bf(acc[2])  | ((unsigned)f2bf(acc[3]) << 16);
        p0.z = (unsigned)f2bf(acc[4])  | ((unsigned)f2bf(acc[5]) << 16);
        p0.w = (unsigned)f2bf(acc[6])  | ((unsigned)f2bf(acc[7]) << 16);
        p1.x = (unsigned)f2bf(acc[8])  | ((unsigned)f2bf(acc[9]) << 16);
        p1.y = (unsigned)f2bf(acc[10]) | ((unsigned)f2bf(acc[11]) << 16);
        p1.z = (unsigned)f2bf(acc[12]) | ((unsigned)f2bf(acc[13]) << 16);
        p1.w = (unsigned)f2bf(acc[14]) | ((unsigned)f2bf(acc[15]) << 16);
        *(uint4*)o = p0;
        *(uint4*)(o + 8) = p1;
    }
}

// ---------------- MFMA GEMM, GBK=64, guard-free (M padded to 50048) ----------------

#define GBM 128
#define GBN 128
#define GBK 64

__global__ __launch_bounds__(256) void gemm_mfma(
    const unsigned short* __restrict__ cat, const unsigned short* __restrict__ WcatT,
    const float* __restrict__ bias, unsigned short* __restrict__ catOut) {
    __shared__ unsigned short sA[GBM][GBK];   // 16 KB
    __shared__ unsigned short sB[GBN][GBK];   // 16 KB

    const int tid = threadIdx.x;
    const int wave = tid >> 6;
    const int lane = tid & 63;
    const int quad = lane >> 4;
    const int l16 = lane & 15;
    const int wm0 = (wave & 1) * 64;
    const int wn0 = (wave >> 1) * 64;
    const int m0 = blockIdx.x * GBM;
    const int n0 = blockIdx.y * GBN;

    const int rowoff = lane >> 3;
    const int schunk = ((lane & 7) ^ rowoff) * 8;   // shorts
    const unsigned short* Asrc[4];
    const unsigned short* Bsrc[4];
#pragma unroll
    for (int j = 0; j < 4; j++) {
        int q = wave * 4 + j;
        Asrc[j] = cat + (size_t)(m0 + q * 8 + rowoff) * K_CAT + schunk;
        Bsrc[j] = WcatT + (size_t)(n0 + q * 8 + rowoff) * K_CAT + schunk;
    }

    const int sw = l16 & 7;
    const int ca0 = (quad ^ sw) * 8;
    const int ca1 = ((4 + quad) ^ sw) * 8;

    float4v acc[4][4] = {};

    for (int kk = 0; kk < K_CAT; kk += GBK) {
#pragma unroll
        for (int j = 0; j < 4; j++) {
            char* da = (char*)sA + (wave * 4 + j) * 1024;
            char* db = (char*)sB + (wave * 4 + j) * 1024;
            async_copy16(da, Asrc[j] + kk);
            async_copy16(db, Bsrc[j] + kk);
        }
        __syncthreads();

        short8 a[4][2], b[4][2];
#pragma unroll
        for (int i = 0; i < 4; i++) {
            const unsigned short* ra = &sA[wm0 + i * 16 + l16][0];
            const unsigned short* rb = &sB[wn0 + i * 16 + l16][0];
            a[i][0] = *(const short8*)(ra + ca0);
            a[i][1] = *(const short8*)(ra + ca1);
            b[i][0] = *(const short8*)(rb + ca0);
            b[i][1] = *(const short8*)(rb + ca1);
        }
#pragma unroll
        for (int sub = 0; sub < 2; sub++)
#pragma unroll
            for (int mi = 0; mi < 4; mi++)
#pragma unroll
                for (int ni = 0; ni < 4; ni++)
                    acc[mi][ni] = __builtin_amdgcn_mfma_f32_16x16x32_bf16(
                        a[mi][sub], b[ni][sub], acc[mi][ni], 0, 0, 0);
        __syncthreads();
    }

#pragma unroll
    for (int ni = 0; ni < 4; ni++) {
        int col = n0 + wn0 + ni * 16 + l16;
        float bc = bias[col];
#pragma unroll
        for (int mi = 0; mi < 4; mi++) {
            int row = m0 + wm0 + mi * 16 + quad * 4;
#pragma unroll
            for (int r = 0; r < 4; r++) {
                float v = acc[mi][ni][r] + bc;
                catOut[(size_t)(row + r) * K_CAT + H + col] = f2bf(fmaxf(v, 0.f));
            }
        }
    }
}

// ---------------- pooling ----------------

__device__ __forceinline__ int lowerBound(const int* __restrict__ batch, int val) {
    int lo = 0, hi = N_NODES;
    while (lo < hi) {
        int mid = (lo + hi) >> 1;
        if (batch[mid] < val) lo = mid + 1; else hi = mid;
    }
    return lo;
}

__global__ void pool_partial(const unsigned short* __restrict__ cat, const int* __restrict__ batch,
                             float* __restrict__ pooled) {
    int g = blockIdx.x;
    int seg = blockIdx.y;
    int f = threadIdx.x;
    int start = lowerBound(batch, g);
    int end = lowerBound(batch, g + 1);
    int len = end - start;
    int s0 = start + (int)((long long)len * seg / 8);
    int s1 = start + (int)((long long)len * (seg + 1) / 8);
    float sum = 0.f;
    for (int n = s0; n < s1; ++n)
        sum += bf2f(cat[(size_t)n * K_CAT + H + f]);
    if (s1 > s0)
        atomicAdd(&pooled[g * H + f], sum);
}

__global__ void head_kernel(const float* __restrict__ pooled, const int* __restrict__ batch,
                            const float* __restrict__ w_out, const float* __restrict__ b_out,
                            float* __restrict__ out) {
    int g = blockIdx.x;
    int o = threadIdx.x;
    int start = lowerBound(batch, g);
    int end = lowerBound(batch, g + 1);
    float cnt = fmaxf((float)(end - start), 1.f);
    float sum = 0.f;
    for (int f = 0; f < H; ++f)
        sum += pooled[g * H + f] * w_out[f * OUT_DIM + o];
    out[g * OUT_DIM + o] = b_out[o] + sum / cnt;
}

// ---------------- launch ----------------

extern "C" void kernel_launch(void* const* d_in, const int* in_sizes, int n_in,
                              void* d_out, int out_size, void* d_ws, size_t ws_size,
                              hipStream_t stream) {
    const float* x      = (const float*)d_in[0];
    const int*   ei     = (const int*)d_in[1];
    const int*   batch  = (const int*)d_in[2];
    const float* w_rel1 = (const float*)d_in[3];
    const float* w_root1= (const float*)d_in[4];
    const float* b1     = (const float*)d_in[5];
    const float* w_rel  = (const float*)d_in[6];
    const float* w_root = (const float*)d_in[7];
    const float* b      = (const float*)d_in[8];
    const float* w_out  = (const float*)d_in[9];
    const float* b_out  = (const float*)d_in[10];
    float* out = (float*)d_out;

    const int* src = ei;
    const int* dst = ei + N_EDGES;

    unsigned short* catA  = (unsigned short*)d_ws;                       // MPAD*512 bf16
    unsigned short* catB  = catA + (size_t)MPAD * K_CAT;                 // MPAD*512 bf16
    unsigned short* WcatT = catB + (size_t)MPAD * K_CAT;                 // 6*256*512 bf16
    float* agg3buf = (float*)(WcatT + (size_t)6 * H * K_CAT);            // N*4 f32
    float* pooled  = agg3buf + (size_t)N_NODES * 4;                      // G*H f32
    float* hscale  = pooled + G_BATCH * H;                               // N f32
    int* rowptr    = (int*)(hscale + N_NODES);                           // N+1
    int* degcur    = rowptr + (N_NODES + 1);                             // N
    int* blockSums = degcur + N_NODES;                                   // 256
    int* csr_src   = blockSums + SCAN_BLK;                               // E
    int* epos      = csr_src + N_EDGES;                                  // E
    unsigned char* h8 = (unsigned char*)(epos + N_EDGES);                // N*256 u8

    // ---- build CSR ----
    hipMemsetAsync(degcur, 0, N_NODES * sizeof(int), stream);
    histo_kernel<<<(N_EDGES + 255) / 256, 256, 0, stream>>>(dst, degcur, epos);
    scan_block<<<NBLK, SCAN_BLK, 0, stream>>>(degcur, rowptr, blockSums);
    scan_sums<<<1, SCAN_BLK, 0, stream>>>(blockSums, rowptr);
    scan_add<<<NBLK, SCAN_BLK, 0, stream>>>(rowptr, blockSums);
    fill_csr<<<(N_EDGES + 255) / 256, 256, 0, stream>>>(src, dst, rowptr, epos, csr_src);

    // ---- weights -> bf16 transposed cat ----
    prep_weights<<<(6 * K_CAT * H + 255) / 256, 256, 0, stream>>>(w_rel, w_root, WcatT);

    // ---- layer 1 (3 -> 256), fp32 ----
    agg3<<<(N_NODES + 255) / 256, 256, 0, stream>>>(x, rowptr, csr_src, agg3buf);
    layer1_kernel<<<N_NODES, H, 0, stream>>>(x, agg3buf, w_rel1, w_root1, b1, catA);

    // ---- layers 2..7 (256 -> 256), int8 gather + bf16 MFMA ----
    unsigned short* cur = catA;
    unsigned short* nxt = catB;
    for (int l = 0; l < 6; ++l) {
        quantH<<<(N_NODES * 64 + 255) / 256, 256, 0, stream>>>(cur, h8, hscale);
        aggH<<<(N_NODES * 64 + 255) / 256, 256, 0, stream>>>(cur, h8, hscale, rowptr, csr_src);
        dim3 grid(MPAD / GBM, H / GBN);
        gemm_mfma<<<grid, 256, 0, stream>>>(cur, WcatT + (size_t)l * H * K_CAT,
                                            b + (size_t)l * H, nxt);
        unsigned short* t = cur; cur = nxt; nxt = t;
    }

    // ---- global mean pool + head ----
    hipMemsetAsync(pooled, 0, G_BATCH * H * sizeof(float), stream);
    pool_partial<<<dim3(G_BATCH, 8), 256, 0, stream>>>(cur, batch, pooled);
    head_kernel<<<G_BATCH, OUT_DIM, 0, stream>>>(pooled, batch, w_out, b_out, out);
}

// Round 8
// 679.989 us; speedup vs baseline: 27.8023x; 1.0064x over previous
//
#include <hip/hip_runtime.h>

#define N_NODES 50000
#define MPAD 50048            // 391 * 128, padded M for guard-free GEMM
#define N_EDGES 800000
#define H 256
#define K_CAT 512
#define G_BATCH 64
#define OUT_DIM 24

#define SCAN_BLK 256
#define NBLK ((N_NODES + SCAN_BLK - 1) / SCAN_BLK)   // 196

typedef __attribute__((ext_vector_type(8))) short short8;
typedef __attribute__((ext_vector_type(4))) float float4v;

__device__ __forceinline__ float bf2f(unsigned short u) {
    return __uint_as_float(((unsigned)u) << 16);
}
__device__ __forceinline__ unsigned short f2bf(float f) {
    unsigned x = __float_as_uint(f);
    unsigned r = (x + 0x7FFFu + ((x >> 16) & 1u)) >> 16;   // RTNE
    return (unsigned short)r;
}

__device__ __forceinline__ void async_copy16(void* lds, const void* g) {
    __builtin_amdgcn_global_load_lds(
        (const __attribute__((address_space(1))) unsigned int*)g,
        (__attribute__((address_space(3))) unsigned int*)lds, 16, 0, 0);
}

// permutation: h8 byte position b holds feature f(b) = (b&0xC0) | ((b&3)<<4) | ((b>>2)&15)
// inverse: feature f stored at b(f) = (f&0xC0) | ((f&15)<<2) | ((f>>4)&3)

// ---------------- CSR build ----------------

__global__ void histo_kernel(const int* __restrict__ dst, int* __restrict__ deg,
                             int* __restrict__ epos) {
    int e = blockIdx.x * blockDim.x + threadIdx.x;
    if (e < N_EDGES) epos[e] = atomicAdd(&deg[dst[e]], 1);
}

__global__ void scan_block(const int* __restrict__ deg, int* __restrict__ rowptr,
                           int* __restrict__ blockSums) {
    __shared__ int s[SCAN_BLK];
    int idx = blockIdx.x * SCAN_BLK + threadIdx.x;
    int v = (idx < N_NODES) ? deg[idx] : 0;
    s[threadIdx.x] = v;
    __syncthreads();
    for (int off = 1; off < SCAN_BLK; off <<= 1) {
        int t = (threadIdx.x >= off) ? s[threadIdx.x - off] : 0;
        __syncthreads();
        s[threadIdx.x] += t;
        __syncthreads();
    }
    if (idx < N_NODES) rowptr[idx] = s[threadIdx.x] - v;
    if (threadIdx.x == SCAN_BLK - 1) blockSums[blockIdx.x] = s[threadIdx.x];
}

// each block redundantly scans the 196 chunk sums, adds its exclusive prefix
__global__ void scan_finish(int* __restrict__ rowptr, const int* __restrict__ blockSums) {
    __shared__ int s[SCAN_BLK];
    int t = threadIdx.x;
    int v = (t < NBLK) ? blockSums[t] : 0;
    s[t] = v;
    __syncthreads();
    for (int off = 1; off < SCAN_BLK; off <<= 1) {
        int tv = (t >= off) ? s[t - off] : 0;
        __syncthreads();
        s[t] += tv;
        __syncthreads();
    }
    int prefix = (blockIdx.x > 0) ? s[blockIdx.x - 1] : 0;
    int idx = blockIdx.x * SCAN_BLK + t;
    if (idx < N_NODES) rowptr[idx] += prefix;
    if (blockIdx.x == 0 && t == 0) rowptr[N_NODES] = s[NBLK - 1];
}

__global__ void fill_csr(const int* __restrict__ src, const int* __restrict__ dst,
                         const int* __restrict__ rowptr, const int* __restrict__ epos,
                         int* __restrict__ csr_src) {
    int e = blockIdx.x * blockDim.x + threadIdx.x;
    if (e >= N_EDGES) return;
    csr_src[rowptr[dst[e]] + epos[e]] = src[e];
}

// ---------------- weight prep (k<256 rows permuted to match h8 byte order) ----------------

__global__ void prep_weights(const float* __restrict__ w_rel, const float* __restrict__ w_root,
                             unsigned short* __restrict__ WcatT) {
    int idx = blockIdx.x * blockDim.x + threadIdx.x;    // 6*512*256
    if (idx >= 6 * K_CAT * H) return;
    int n = idx & (H - 1);
    int k = (idx >> 8) & (K_CAT - 1);
    int l = idx >> 17;
    float v;
    if (k < H) {
        int f = (k & 0xC0) | ((k & 3) << 4) | ((k >> 2) & 15);   // feature at slot k
        v = w_rel[(size_t)l * H * H + f * H + n];
    } else {
        v = w_root[(size_t)l * H * H + (k - H) * H + n];
    }
    WcatT[(size_t)l * H * K_CAT + (size_t)n * K_CAT + k] = f2bf(v);
}

// ---------------- layer 1 (F_IN=3 -> H) ----------------

__global__ void agg3(const float* __restrict__ x, const int* __restrict__ rowptr,
                     const int* __restrict__ csr_src, float* __restrict__ agg) {
    int n = blockIdx.x * blockDim.x + threadIdx.x;
    if (n >= N_NODES) return;
    int beg = rowptr[n], end = rowptr[n + 1];
    float a0 = 0.f, a1 = 0.f, a2 = 0.f;
    for (int i = beg; i < end; ++i) {
        int s = csr_src[i];
        a0 += x[s * 3 + 0];
        a1 += x[s * 3 + 1];
        a2 += x[s * 3 + 2];
    }
    agg[n * 3 + 0] = a0;
    agg[n * 3 + 1] = a1;
    agg[n * 3 + 2] = a2;
}

// also emits permuted u8 h + per-64-col-group scales
__global__ void layer1_kernel(const float* __restrict__ x, const float* __restrict__ agg,
                              const float* __restrict__ wr, const float* __restrict__ wro,
                              const float* __restrict__ bias, unsigned short* __restrict__ cat,
                              unsigned char* __restrict__ h8, float* __restrict__ hscale) {
    __shared__ unsigned char tmp[H];
    int n = blockIdx.x;
    int f = threadIdx.x;
    float a0 = agg[n * 3 + 0], a1 = agg[n * 3 + 1], a2 = agg[n * 3 + 2];
    float x0 = x[n * 3 + 0], x1 = x[n * 3 + 1], x2 = x[n * 3 + 2];
    float v = bias[f];
    v += a0 * wr[0 * H + f] + a1 * wr[1 * H + f] + a2 * wr[2 * H + f];
    v += x0 * wro[0 * H + f] + x1 * wro[1 * H + f] + x2 * wro[2 * H + f];
    v = fmaxf(v, 0.f);
    cat[(size_t)n * K_CAT + H + f] = f2bf(v);
    // per-wave (= per 64-feature group) max
    float m = v;
#pragma unroll
    for (int off = 1; off < 64; off <<= 1) m = fmaxf(m, __shfl_xor(m, off, 64));
    float inv = m > 0.f ? 255.f / m : 0.f;
    tmp[(f & 0xC0) | ((f & 15) << 2) | ((f >> 4) & 3)] = (unsigned char)(v * inv + 0.5f);
    if ((f & 63) == 0) hscale[n * 4 + (f >> 6)] = m * (1.f / 255.f);
    __syncthreads();
    if (f < 64) *(unsigned*)(h8 + (size_t)n * H + f * 4) = *(const unsigned*)(tmp + f * 4);
}

// ---------------- gather-aggregate from u8 rows, software-pipelined ----------------
// one wave per node; 4 sub-groups of 16 lanes cover 4 edges per load; lane group fl
// covers h8 bytes fl*16..+15 (col-group g = fl>>2). Output agg is in permuted order
// (matches WcatT k<256).

__global__ __launch_bounds__(256) void aggH(unsigned short* __restrict__ cat,
                                            const unsigned char* __restrict__ h8,
                                            const float* __restrict__ hscale,
                                            const int* __restrict__ rowptr,
                                            const int* __restrict__ csr_src) {
    int gtid = blockIdx.x * blockDim.x + threadIdx.x;
    int node = gtid >> 6;
    if (node >= N_NODES) return;
    int lane = threadIdx.x & 63;
    int sub = lane >> 4;
    int fl = lane & 15;
    int g = fl >> 2;
    int beg = rowptr[node], end = rowptr[node + 1];

    if (beg >= end) {
        if (sub == 0) {
            uint4 z = make_uint4(0, 0, 0, 0);
            unsigned short* o = cat + (size_t)node * K_CAT + fl * 16;
            *(uint4*)o = z;
            *(uint4*)(o + 8) = z;
        }
        return;
    }

    float acc[16] = {};
    const unsigned char* base = h8 + fl * 16;
    int last = end - 1;

    // pipeline: sa/sca/qa = current, sb = next index in flight
    int ia = beg + sub;
    int ca = ia < end ? ia : last;
    int sa = csr_src[ca];
    int ib = beg + 4 + sub;
    int cb = ib < end ? ib : last;
    int sb = csr_src[cb];
    float sca = (ia < end) ? hscale[sa * 4 + g] : 0.f;
    uint4 qa = *(const uint4*)(base + (size_t)sa * H);

    for (int i = beg; i < end; i += 4) {
        // prefetch index for i+8, row/scale for i+4
        int ic = i + 8 + sub;
        int cc = ic < end ? ic : last;
        int sn = csr_src[cc];
        int inb = i + 4 + sub;
        float scb = (inb < end) ? hscale[sb * 4 + g] : 0.f;
        uint4 qb = *(const uint4*)(base + (size_t)sb * H);

        float sc = sca;
        acc[0]  = fmaf((float)(qa.x & 0xffu), sc, acc[0]);
        acc[1]  = fmaf((float)((qa.x >> 8) & 0xffu), sc, acc[1]);
        acc[2]  = fmaf((float)((qa.x >> 16) & 0xffu), sc, acc[2]);
        acc[3]  = fmaf((float)(qa.x >> 24), sc, acc[3]);
        acc[4]  = fmaf((float)(qa.y & 0xffu), sc, acc[4]);
        acc[5]  = fmaf((float)((qa.y >> 8) & 0xffu), sc, acc[5]);
        acc[6]  = fmaf((float)((qa.y >> 16) & 0xffu), sc, acc[6]);
        acc[7]  = fmaf((float)(qa.y >> 24), sc, acc[7]);
        acc[8]  = fmaf((float)(qa.z & 0xffu), sc, acc[8]);
        acc[9]  = fmaf((float)((qa.z >> 8) & 0xffu), sc, acc[9]);
        acc[10] = fmaf((float)((qa.z >> 16) & 0xffu), sc, acc[10]);
        acc[11] = fmaf((float)(qa.z >> 24), sc, acc[11]);
        acc[12] = fmaf((float)(qa.w & 0xffu), sc, acc[12]);
        acc[13] = fmaf((float)((qa.w >> 8) & 0xffu), sc, acc[13]);
        acc[14] = fmaf((float)((qa.w >> 16) & 0xffu), sc, acc[14]);
        acc[15] = fmaf((float)(qa.w >> 24), sc, acc[15]);

        sa = sb; sb = sn; sca = scb; qa = qb;
    }

#pragma unroll
    for (int j = 0; j < 16; j++) {
        acc[j] += __shfl_xor(acc[j], 16, 64);
        acc[j] += __shfl_xor(acc[j], 32, 64);
    }

    if (sub == 0) {
        unsigned short* o = cat + (size_t)node * K_CAT + fl * 16;
        uint4 p0, p1;
        p0.x = (unsigned)f2bf(acc[0])  | ((unsigned)f2bf(acc[1]) << 16);
        p0.y = (unsigned)f2bf(acc[2])  | ((unsigned)f2bf(acc[3]) << 16);
        p0.z = (unsigned)f2bf(acc[4])  | ((unsigned)f2bf(acc[5]) << 16);
        p0.w = (unsigned)f2bf(acc[6])  | ((unsigned)f2bf(acc[7]) << 16);
        p1.x = (unsigned)f2bf(acc[8])  | ((unsigned)f2bf(acc[9]) << 16);
        p1.y = (unsigned)f2bf(acc[10]) | ((unsigned)f2bf(acc[11]) << 16);
        p1.z = (unsigned)f2bf(acc[12]) | ((unsigned)f2bf(acc[13]) << 16);
        p1.w = (unsigned)f2bf(acc[14]) | ((unsigned)f2bf(acc[15]) << 16);
        *(uint4*)o = p0;
        *(uint4*)(o + 8) = p1;
    }
}

// ---------------- MFMA GEMM, GBK=64, guard-free; epilogue emits bf16 h + u8 h + scales ----

#define GBM 128
#define GBN 128
#define GBK 64

__global__ __launch_bounds__(256) void gemm_mfma(
    const unsigned short* __restrict__ cat, const unsigned short* __restrict__ WcatT,
    const float* __restrict__ bias, unsigned short* __restrict__ catOut,
    unsigned char* __restrict__ h8, float* __restrict__ hscale) {
    __shared__ unsigned short sA[GBM][GBK];   // 16 KB
    __shared__ unsigned short sB[GBN][GBK];   // 16 KB

    const int tid = threadIdx.x;
    const int wave = tid >> 6;
    const int lane = tid & 63;
    const int quad = lane >> 4;
    const int l16 = lane & 15;
    const int wm0 = (wave & 1) * 64;
    const int wn0 = (wave >> 1) * 64;
    const int m0 = blockIdx.x * GBM;
    const int n0 = blockIdx.y * GBN;

    const int rowoff = lane >> 3;
    const int schunk = ((lane & 7) ^ rowoff) * 8;   // shorts
    const unsigned short* Asrc[4];
    const unsigned short* Bsrc[4];
#pragma unroll
    for (int j = 0; j < 4; j++) {
        int q = wave * 4 + j;
        Asrc[j] = cat + (size_t)(m0 + q * 8 + rowoff) * K_CAT + schunk;
        Bsrc[j] = WcatT + (size_t)(n0 + q * 8 + rowoff) * K_CAT + schunk;
    }

    const int sw = l16 & 7;
    const int ca0 = (quad ^ sw) * 8;
    const int ca1 = ((4 + quad) ^ sw) * 8;

    float4v acc[4][4] = {};

    for (int kk = 0; kk < K_CAT; kk += GBK) {
#pragma unroll
        for (int j = 0; j < 4; j++) {
            char* da = (char*)sA + (wave * 4 + j) * 1024;
            char* db = (char*)sB + (wave * 4 + j) * 1024;
            async_copy16(da, Asrc[j] + kk);
            async_copy16(db, Bsrc[j] + kk);
        }
        __syncthreads();

        short8 a[4][2], b[4][2];
#pragma unroll
        for (int i = 0; i < 4; i++) {
            const unsigned short* ra = &sA[wm0 + i * 16 + l16][0];
            const unsigned short* rb = &sB[wn0 + i * 16 + l16][0];
            a[i][0] = *(const short8*)(ra + ca0);
            a[i][1] = *(const short8*)(ra + ca1);
            b[i][0] = *(const short8*)(rb + ca0);
            b[i][1] = *(const short8*)(rb + ca1);
        }
#pragma unroll
        for (int sub = 0; sub < 2; sub++)
#pragma unroll
            for (int mi = 0; mi < 4; mi++)
#pragma unroll
                for (int ni = 0; ni < 4; ni++)
                    acc[mi][ni] = __builtin_amdgcn_mfma_f32_16x16x32_bf16(
                        a[mi][sub], b[ni][sub], acc[mi][ni], 0, 0, 0);
        __syncthreads();
    }

    // epilogue: bias+relu, bf16 h, u8 h (permuted layout -> contiguous u32), group scale
    const int hb = n0 + wn0 + l16 * 4;
    const int gsc = (n0 + wn0) >> 6;
    float bcol[4];
#pragma unroll
    for (int ni = 0; ni < 4; ni++) bcol[ni] = bias[n0 + wn0 + ni * 16 + l16];

#pragma unroll
    for (int mi = 0; mi < 4; mi++) {
        int rowb = m0 + wm0 + mi * 16 + quad * 4;
#pragma unroll
        for (int r = 0; r < 4; r++) {
            int row = rowb + r;
            float v0 = fmaxf(acc[mi][0][r] + bcol[0], 0.f);
            float v1 = fmaxf(acc[mi][1][r] + bcol[1], 0.f);
            float v2 = fmaxf(acc[mi][2][r] + bcol[2], 0.f);
            float v3 = fmaxf(acc[mi][3][r] + bcol[3], 0.f);
            unsigned short* co = catOut + (size_t)row * K_CAT + H + n0 + wn0 + l16;
            co[0]  = f2bf(v0);
            co[16] = f2bf(v1);
            co[32] = f2bf(v2);
            co[48] = f2bf(v3);
            float m = fmaxf(fmaxf(v0, v1), fmaxf(v2, v3));
            m = fmaxf(m, __shfl_xor(m, 1, 64));
            m = fmaxf(m, __shfl_xor(m, 2, 64));
            m = fmaxf(m, __shfl_xor(m, 4, 64));
            m = fmaxf(m, __shfl_xor(m, 8, 64));
            float inv = m > 0.f ? 255.f / m : 0.f;
            unsigned p = (unsigned)(v0 * inv + 0.5f)
                       | ((unsigned)(v1 * inv + 0.5f) << 8)
                       | ((unsigned)(v2 * inv + 0.5f) << 16)
                       | ((unsigned)(v3 * inv + 0.5f) << 24);
            *(unsigned*)(h8 + (size_t)row * H + hb) = p;
            if (l16 == 0) hscale[row * 4 + gsc] = m * (1.f / 255.f);
        }
    }
}

// ---------------- pooling ----------------

__device__ __forceinline__ int lowerBound(const int* __restrict__ batch, int val) {
    int lo = 0, hi = N_NODES;
    while (lo < hi) {
        int mid = (lo + hi) >> 1;
        if (batch[mid] < val) lo = mid + 1; else hi = mid;
    }
    return lo;
}

__global__ void pool_partial(const unsigned short* __restrict__ cat, const int* __restrict__ batch,
                             float* __restrict__ pooled) {
    int g = blockIdx.x;
    int seg = blockIdx.y;
    int f = threadIdx.x;
    int start = lowerBound(batch, g);
    int end = lowerBound(batch, g + 1);
    int len = end - start;
    int s0 = start + (int)((long long)len * seg / 8);
    int s1 = start + (int)((long long)len * (seg + 1) / 8);
    float sum = 0.f;
    for (int n = s0; n < s1; ++n)
        sum += bf2f(cat[(size_t)n * K_CAT + H + f]);
    if (s1 > s0)
        atomicAdd(&pooled[g * H + f], sum);
}

__global__ void head_kernel(const float* __restrict__ pooled, const int* __restrict__ batch,
                            const float* __restrict__ w_out, const float* __restrict__ b_out,
                            float* __restrict__ out) {
    int g = blockIdx.x;
    int o = threadIdx.x;
    int start = lowerBound(batch, g);
    int end = lowerBound(batch, g + 1);
    float cnt = fmaxf((float)(end - start), 1.f);
    float sum = 0.f;
    for (int f = 0; f < H; ++f)
        sum += pooled[g * H + f] * w_out[f * OUT_DIM + o];
    out[g * OUT_DIM + o] = b_out[o] + sum / cnt;
}

// ---------------- launch ----------------

extern "C" void kernel_launch(void* const* d_in, const int* in_sizes, int n_in,
                              void* d_out, int out_size, void* d_ws, size_t ws_size,
                              hipStream_t stream) {
    const float* x      = (const float*)d_in[0];
    const int*   ei     = (const int*)d_in[1];
    const int*   batch  = (const int*)d_in[2];
    const float* w_rel1 = (const float*)d_in[3];
    const float* w_root1= (const float*)d_in[4];
    const float* b1     = (const float*)d_in[5];
    const float* w_rel  = (const float*)d_in[6];
    const float* w_root = (const float*)d_in[7];
    const float* b      = (const float*)d_in[8];
    const float* w_out  = (const float*)d_in[9];
    const float* b_out  = (const float*)d_in[10];
    float* out = (float*)d_out;

    const int* src = ei;
    const int* dst = ei + N_EDGES;

    unsigned short* catA  = (unsigned short*)d_ws;                       // MPAD*512 bf16
    unsigned short* catB  = catA + (size_t)MPAD * K_CAT;                 // MPAD*512 bf16
    unsigned short* WcatT = catB + (size_t)MPAD * K_CAT;                 // 6*256*512 bf16
    float* agg3buf = (float*)(WcatT + (size_t)6 * H * K_CAT);            // N*4 f32
    float* pooled  = agg3buf + (size_t)N_NODES * 4;                      // G*H f32
    float* hscale  = pooled + G_BATCH * H;                               // MPAD*4 f32
    int* rowptr    = (int*)(hscale + (size_t)MPAD * 4);                  // N+1
    int* degcur    = rowptr + (N_NODES + 1);                             // N
    int* blockSums = degcur + N_NODES;                                   // 256
    int* csr_src   = blockSums + SCAN_BLK;                               // E
    int* epos      = csr_src + N_EDGES;                                  // E
    unsigned char* h8 = (unsigned char*)(epos + N_EDGES);                // MPAD*256 u8

    // ---- build CSR ----
    hipMemsetAsync(degcur, 0, N_NODES * sizeof(int), stream);
    histo_kernel<<<(N_EDGES + 255) / 256, 256, 0, stream>>>(dst, degcur, epos);
    scan_block<<<NBLK, SCAN_BLK, 0, stream>>>(degcur, rowptr, blockSums);
    scan_finish<<<NBLK, SCAN_BLK, 0, stream>>>(rowptr, blockSums);
    fill_csr<<<(N_EDGES + 255) / 256, 256, 0, stream>>>(src, dst, rowptr, epos, csr_src);

    // ---- weights -> bf16 transposed cat (k<256 permuted) ----
    prep_weights<<<(6 * K_CAT * H + 255) / 256, 256, 0, stream>>>(w_rel, w_root, WcatT);

    // ---- layer 1 (3 -> 256), fp32, emits bf16 h + u8 h + scales ----
    agg3<<<(N_NODES + 255) / 256, 256, 0, stream>>>(x, rowptr, csr_src, agg3buf);
    layer1_kernel<<<N_NODES, H, 0, stream>>>(x, agg3buf, w_rel1, w_root1, b1, catA, h8, hscale);

    // ---- layers 2..7 (256 -> 256), u8 gather + bf16 MFMA ----
    unsigned short* cur = catA;
    unsigned short* nxt = catB;
    for (int l = 0; l < 6; ++l) {
        aggH<<<(N_NODES * 64 + 255) / 256, 256, 0, stream>>>(cur, h8, hscale, rowptr, csr_src);
        dim3 grid(MPAD / GBM, H / GBN);
        gemm_mfma<<<grid, 256, 0, stream>>>(cur, WcatT + (size_t)l * H * K_CAT,
                                            b + (size_t)l * H, nxt, h8, hscale);
        unsigned short* t = cur; cur = nxt; nxt = t;
    }

    // ---- global mean pool + head ----
    hipMemsetAsync(pooled, 0, G_BATCH * H * sizeof(float), stream);
    pool_partial<<<dim3(G_BATCH, 8), 256, 0, stream>>>(cur, batch, pooled);
    head_kernel<<<G_BATCH, OUT_DIM, 0, stream>>>(pooled, batch, w_out, b_out, out);
}